// Round 12
// baseline (106.960 us; speedup 1.0000x reference)
//
#include <hip/hip_runtime.h>
#include <stdint.h>

#define NTOK 256
#define NOUT 128
#define DIM 64
#define NB 128
#define NSEG 4
#define LCAP 384          // keys per segment (expected ~224, +10.6 sigma)
#define KTOT 1536         // NSEG * LCAP
#define WCAP 1024         // fast-path sort capacity (empirically >= all batches)
#define PCAPA 512
#define NMERGE 128
#define KAPPA 0.24f
#define SCREEN 0.2395f
#define NTILES84 1056
#define TILES_PER_SUB84 264
#define KNT_ELEMS (DIM * NTOK)   // 16384 floats = 64KB

__device__ __forceinline__ unsigned mono_f32(float s) {
  unsigned u = __float_as_uint(s);
  return (u & 0x80000000u) ? ~u : (u | 0x80000000u);
}

__device__ __forceinline__ unsigned long long shflx64(unsigned long long x, int m) {
  unsigned lo = (unsigned)x, hi = (unsigned)(x >> 32);
  lo = __shfl_xor(lo, m);
  hi = __shfl_xor(hi, m);
  return ((unsigned long long)hi << 32) | lo;
}

// invert T -> (ti, tj) on the 8x4 tile grid: ti in [0,32), tj in [2*ti, 64)
__device__ __forceinline__ void tile84(int T, int& tio, int& tjo) {
  float tf = (65.0f - sqrtf(4225.0f - 4.0f * (float)T)) * 0.5f;
  int t = (int)tf;
  if (t < 0) t = 0;
  if (t > 31) t = 31;
  while (t < 31 && 65 * (t + 1) - (t + 1) * (t + 1) <= T) ++t;
  while (t > 0 && 65 * t - t * t > T) --t;
  tio = t;
  tjo = 2 * t + (T - (65 * t - t * t));
}

#define CEX(a, b, up)                         \
  do {                                        \
    unsigned long long _a = (a), _b = (b);    \
    bool _sw = (up) ? (_a < _b) : (_a > _b);  \
    if (_sw) { (a) = _b; (b) = _a; }          \
  } while (0)

#define KEEP(v, o, km) ((km) ? ((v) > (o) ? (v) : (o)) : ((v) < (o) ? (v) : (o)))

// ---- 256-thread normalize chain (bit-identical to all prior rounds) ----
__device__ __forceinline__ void norm_vals(const float* __restrict__ kp,
                                          float* __restrict__ vals,
                                          double& nrm) {
  double s0 = 0.0, s1 = 0.0;
#pragma unroll
  for (int q = 0; q < 8; ++q) {
    float4 v4 = *reinterpret_cast<const float4*>(kp + q * 4);
    vals[q * 4 + 0] = v4.x; vals[q * 4 + 1] = v4.y;
    vals[q * 4 + 2] = v4.z; vals[q * 4 + 3] = v4.w;
    s0 += (double)v4.x * v4.x + (double)v4.y * v4.y +
          (double)v4.z * v4.z + (double)v4.w * v4.w;
  }
#pragma unroll
  for (int q = 8; q < 16; ++q) {
    float4 v4 = *reinterpret_cast<const float4*>(kp + q * 4);
    vals[q * 4 + 0] = v4.x; vals[q * 4 + 1] = v4.y;
    vals[q * 4 + 2] = v4.z; vals[q * 4 + 3] = v4.w;
    s1 += (double)v4.x * v4.x + (double)v4.y * v4.y +
          (double)v4.z * v4.z + (double)v4.w * v4.w;
  }
  nrm = sqrt(s0 + s1);
}

// ---- 512-thread normalize (gm_fused fallback only) ----
__device__ __forceinline__ void normalize_to_knT(const float* __restrict__ K,
                                                 float* __restrict__ knT,
                                                 int b, int tid) {
  const int t = tid >> 1, h = tid & 1;
  const float* kp = K + ((size_t)b * NTOK + t) * DIM + h * 32;
  double ss = 0.0;
  float vals[32];
#pragma unroll
  for (int q = 0; q < 8; ++q) {
    float4 v4 = *reinterpret_cast<const float4*>(kp + q * 4);
    vals[q * 4 + 0] = v4.x; vals[q * 4 + 1] = v4.y;
    vals[q * 4 + 2] = v4.z; vals[q * 4 + 3] = v4.w;
    ss += (double)v4.x * v4.x + (double)v4.y * v4.y +
          (double)v4.z * v4.z + (double)v4.w * v4.w;
  }
  double other = __shfl_xor(ss, 1);
  double nrm = sqrt(ss + other);
#pragma unroll
  for (int q = 0; q < 32; ++q)
    knT[(h * 32 + q) * NTOK + t] = (float)((double)vals[q] / nrm);
}

// ============ kernel 0: normalize once per batch -> knTg[b][d][t] ============
// grid 128, block 256. Coalesced stores (threads = tokens).
__global__ __launch_bounds__(256) void gm_norm(const float* __restrict__ K,
                                               float* __restrict__ knTg) {
  const int t = threadIdx.x;
  const int b = blockIdx.x;
  const float* kp = K + ((size_t)b * NTOK + t) * DIM;
  float vals[64];
  double nrm;
  norm_vals(kp, vals, nrm);
  float* dst = knTg + (size_t)b * KNT_ELEMS;
#pragma unroll
  for (int d = 0; d < 64; ++d)
    dst[d * NTOK + t] = (float)((double)vals[d] / nrm);
}

// ============ kernel 1: gram screen + exact f64 + fixed-segment flush ============
// grid 512 (4 WGs/batch), block 256, 2 blocks/CU exactly.
// LDS: knT 64KB @0, lpairs 2KB @65536, lkeys 3KB @67584, lmisc @70656
#define SMEM_A 70672
__global__ __launch_bounds__(256) void gm_gram(const float* __restrict__ knTg,
                                               unsigned* __restrict__ gcnt,
                                               unsigned long long* __restrict__ gkeys) {
  extern __shared__ char smem[];
  float* knT = (float*)smem;
  unsigned* lpairs = (unsigned*)(smem + 65536);
  unsigned long long* lkeys = (unsigned long long*)(smem + 67584);
  int* lmisc = (int*)(smem + 70656);

  const int tid = threadIdx.x;
  const int b = blockIdx.x >> 2, sub = blockIdx.x & 3;

  if (tid == 0) { lmisc[0] = 0; lmisc[1] = 0; }
  // coalesced knTg -> LDS copy (float4)
  {
    const float4* src = reinterpret_cast<const float4*>(knTg + (size_t)b * KNT_ELEMS);
    float4* dst = reinterpret_cast<float4*>(knT);
#pragma unroll
    for (int e = 0; e < KNT_ELEMS / 4 / 256; ++e)
      dst[e * 256 + tid] = src[e * 256 + tid];
  }
  __syncthreads();

  const int base = sub * TILES_PER_SUB84;
  for (int t = tid; t < TILES_PER_SUB84; t += 256) {
    int ti, tj;
    tile84(base + t, ti, tj);
    const int i0 = ti * 8, j0 = tj * 4;

    float acc[8][4] = {};
#pragma unroll 4
    for (int d = 0; d < 64; ++d) {
      const float* row = knT + d * NTOK;
      const float4 a0 = *reinterpret_cast<const float4*>(row + i0);
      const float4 a1 = *reinterpret_cast<const float4*>(row + i0 + 4);
      const float4 bv = *reinterpret_cast<const float4*>(row + j0);
      const float aa[8] = {a0.x, a0.y, a0.z, a0.w, a1.x, a1.y, a1.z, a1.w};
      const float bb[4] = {bv.x, bv.y, bv.z, bv.w};
#pragma unroll
      for (int r = 0; r < 8; ++r)
#pragma unroll
        for (int c = 0; c < 4; ++c)
          acc[r][c] = fmaf(aa[r], bb[c], acc[r][c]);
    }
#pragma unroll
    for (int r = 0; r < 8; ++r)
#pragma unroll
      for (int c = 0; c < 4; ++c) {
        const int i = i0 + r, j = j0 + c;
        if (i < j && acc[r][c] >= SCREEN) {
          const int idx = atomicAdd(&lmisc[0], 1);
          if (idx < PCAPA) lpairs[idx] = (unsigned)((i << 8) | j);
        }
      }
  }
  __syncthreads();

  const int npRaw = lmisc[0];
  const int np = npRaw > PCAPA ? PCAPA : npRaw;
  for (int e = tid; e < np; e += 256) {
    const unsigned p = lpairs[e];
    const int i = (int)(p >> 8), j = (int)(p & 255u);
    double s = 0.0;
    for (int d = 0; d < 64; ++d)
      s = fma((double)knT[d * NTOK + i], (double)knT[d * NTOK + j], s);
    const float sf = (float)s;
    if (sf >= KAPPA) {
      const unsigned long long key =
          ((unsigned long long)mono_f32(sf) << 16) |
          (unsigned)(65535 - ((i << 8) | j));
      const int idx = atomicAdd(&lmisc[1], 1);
      if (idx < LCAP) lkeys[idx] = key;
    }
  }
  __syncthreads();

  const int nkRaw = lmisc[1];
  if (tid == 0)
    gcnt[NSEG * b + sub] =
        (npRaw > PCAPA || nkRaw > LCAP) ? 0x7FFFFFFFu : (unsigned)nkRaw;
  const int nk = nkRaw > LCAP ? LCAP : nkRaw;
  unsigned long long* seg = gkeys + (size_t)b * KTOT + (size_t)sub * LCAP;
  for (int e = tid; e < nk; e += 256) seg[e] = lkeys[e];
}

// ---- shared helper: segment counts -> clamped sizes + prefix + flags ----
__device__ __forceinline__ void seg_info(const unsigned* __restrict__ gcnt, int b,
                                         int n[NSEG], int offs[NSEG], int& cntC,
                                         bool& fast) {
  bool ovf = false;
  int run = 0;
#pragma unroll
  for (int s = 0; s < NSEG; ++s) {
    const unsigned m = gcnt[NSEG * b + s];
    if (m > LCAP) ovf = true;
    n[s] = m > LCAP ? LCAP : (int)m;
    offs[s] = run;
    run += n[s];
  }
  cntC = run;
  fast = !ovf && (cntC <= WCAP);
}

// ============ kernel 2: packed load + bitonic sort 1024 -> gkeys (in place) ============
// grid 128, block 256, static 8KB LDS.
__global__ __launch_bounds__(256) void gm_sort(const unsigned* __restrict__ gcnt,
                                               unsigned long long* __restrict__ gkeys) {
  __shared__ unsigned long long keys[WCAP];
  const int tid = threadIdx.x;
  const int b = blockIdx.x;

  int n[NSEG], offs[NSEG], cntC;
  bool fast;
  seg_info(gcnt, b, n, offs, cntC, fast);

  unsigned long long* gk = gkeys + (size_t)b * KTOT;
  for (int dst = tid; dst < WCAP; dst += 256) {
    unsigned long long v = 0ULL;
    if (fast && dst < cntC) {
      int seg = 0, base = 0;
#pragma unroll
      for (int s = 1; s < NSEG; ++s)
        if (dst >= offs[s]) { seg = s; base = offs[s]; }
      v = gk[seg * LCAP + (dst - base)];
    }
    keys[dst] = v;
  }
  __syncthreads();

  {
    const int e0 = 4 * tid;
    unsigned long long v0 = keys[e0], v1 = keys[e0 + 1],
                       v2 = keys[e0 + 2], v3 = keys[e0 + 3];
    for (int kk = 2; kk <= WCAP; kk <<= 1) {
      for (int jj = kk >> 1; jj > 0; jj >>= 1) {
        if (jj >= 256) {
          __syncthreads();
          keys[e0] = v0; keys[e0 + 1] = v1; keys[e0 + 2] = v2; keys[e0 + 3] = v3;
          __syncthreads();
          const int p0 = e0 ^ jj;
          unsigned long long o0 = keys[p0], o1 = keys[p0 + 1],
                             o2 = keys[p0 + 2], o3 = keys[p0 + 3];
          const bool km = ((e0 & kk) == 0) == ((e0 & jj) == 0);
          v0 = KEEP(v0, o0, km); v1 = KEEP(v1, o1, km);
          v2 = KEEP(v2, o2, km); v3 = KEEP(v3, o3, km);
        } else if (jj >= 4) {
          const int m = jj >> 2;
          unsigned long long o0 = shflx64(v0, m), o1 = shflx64(v1, m),
                             o2 = shflx64(v2, m), o3 = shflx64(v3, m);
          const bool km = ((e0 & kk) == 0) == ((e0 & jj) == 0);
          v0 = KEEP(v0, o0, km); v1 = KEEP(v1, o1, km);
          v2 = KEEP(v2, o2, km); v3 = KEEP(v3, o3, km);
        } else if (jj == 2) {
          const bool up = ((e0 & kk) == 0);
          CEX(v0, v2, up); CEX(v1, v3, up);
        } else {
          bool up0, up1;
          if (kk == 2) { up0 = true; up1 = false; }
          else { up0 = up1 = ((e0 & kk) == 0); }
          CEX(v0, v1, up0); CEX(v2, v3, up1);
        }
      }
    }
    gk[e0] = v0; gk[e0 + 1] = v1; gk[e0 + 2] = v2; gk[e0 + 3] = v3;
  }
}

// ============ kernel 3: serial-shfl walk + cheap exact fallback -> gid ============
// grid 128, block 256, dynamic LDS.
// LDS: knT 64KB @0 (fallback only), keys 8KB @65536, gid @73728,
//      misc @74752, red @74768, bkey @74800
#define SMEM_K 74816
__global__ __launch_bounds__(256) void gm_walk(const float* __restrict__ knTg,
                                               const unsigned* __restrict__ gcnt,
                                               const unsigned long long* __restrict__ gkeys,
                                               int* __restrict__ gidg) {
  extern __shared__ char smem[];
  float* knT = (float*)smem;
  unsigned long long* keys = (unsigned long long*)(smem + 65536);
  int* gid = (int*)(smem + 73728);
  int* misc = (int*)(smem + 74752);
  unsigned long long* red = (unsigned long long*)(smem + 74768);
  unsigned long long* bkey = (unsigned long long*)(smem + 74800);

  const int tid = threadIdx.x;
  const int lane = tid & 63;
  const int wid = tid >> 6;
  const int b = blockIdx.x;

  int n[NSEG], offs[NSEG], cntC;
  bool fast;
  seg_info(gcnt, b, n, offs, cntC, fast);

  if (tid == 0) misc[3] = fast ? NMERGE : 0;
  gid[tid] = tid;
  {
    const unsigned long long* gk = gkeys + (size_t)b * KTOT;
#pragma unroll
    for (int r = 0; r < 4; ++r) keys[4 * tid + r] = gk[4 * tid + r];
  }
  __syncthreads();

  if (fast && wid == 0) {
    int rg0 = lane, rg1 = 64 + lane, rg2 = 128 + lane, rg3 = 192 + lane;
    int done = 0;
    for (int cursor = 0; cursor < cntC && done < NMERGE; cursor += 64) {
      const int idx = cursor + lane;
      const unsigned long long key = (idx < cntC) ? keys[idx] : 0ULL;
      const int pi = 255 - (int)((key >> 8) & 255);
      const int pj = 255 - (int)(key & 255);
      const int sli = pi & 63, ssi = pi >> 6;
      const int slj = pj & 63, ssj = pj >> 6;
      const int a0 = __shfl(rg0, sli), a1 = __shfl(rg1, sli),
                a2 = __shfl(rg2, sli), a3 = __shfl(rg3, sli);
      const int b0 = __shfl(rg0, slj), b1 = __shfl(rg1, slj),
                b2 = __shfl(rg2, slj), b3 = __shfl(rg3, slj);
      int gpi = (ssi == 0) ? a0 : (ssi == 1) ? a1 : (ssi == 2) ? a2 : a3;
      int gpj = (ssj == 0) ? b0 : (ssj == 1) ? b1 : (ssj == 2) ? b2 : b3;
      if (key == 0ULL) { gpi = 0; gpj = 0; }
      for (;;) {
        const unsigned long long mask = __ballot(gpi != gpj);
        if (!mask) break;
        const int f = __ffsll((long long)mask) - 1;
        const int gij = __shfl((gpi << 8) | gpj, f);
        const int gi = gij >> 8, gj = gij & 255;
        if (gpi == gi) gpi = gj;
        if (gpj == gi) gpj = gj;
        if (rg0 == gi) rg0 = gj;
        if (rg1 == gi) rg1 = gj;
        if (rg2 == gi) rg2 = gj;
        if (rg3 == gi) rg3 = gj;
        if (++done == NMERGE) break;
      }
    }
    gid[lane] = rg0; gid[64 + lane] = rg1;
    gid[128 + lane] = rg2; gid[192 + lane] = rg3;
    if (lane == 0) misc[3] = done;
  }
  __syncthreads();

  // cheap exact fallback: load knTg into LDS (bit-identical values), argmax
  {
    const int start = misc[3];
    if (start < NMERGE) {
      {
        const float4* src = reinterpret_cast<const float4*>(knTg + (size_t)b * KNT_ELEMS);
        float4* dst = reinterpret_cast<float4*>(knT);
#pragma unroll
        for (int e = 0; e < KNT_ELEMS / 4 / 256; ++e)
          dst[e * 256 + tid] = src[e * 256 + tid];
      }
      __syncthreads();
      for (int mg = start; mg < NMERGE; ++mg) {
        unsigned long long best = 0ULL;
        const int p = tid >> 1, q = tid & 1;
        const int jA = 128 + p, jB = 127 - p;
        const int lenA = jA;
        const int s0 = q * 128, s1 = (q == 1) ? 255 : 128;
        for (int e = s0; e < s1; ++e) {
          const int i = (e < lenA) ? e : (e - lenA);
          const int j = (e < lenA) ? jA : jB;
          if (gid[i] != gid[j]) {
            double s = 0.0;
            for (int d = 0; d < 64; ++d)
              s = fma((double)knT[d * NTOK + i], (double)knT[d * NTOK + j], s);
            const unsigned long long key =
                ((unsigned long long)mono_f32((float)s) << 16) |
                (unsigned)(65535 - ((i << 8) | j));
            if (key > best) best = key;
          }
        }
#pragma unroll
        for (int off = 32; off; off >>= 1) {
          unsigned long long o = __shfl_down(best, off);
          if (o > best) best = o;
        }
        if (lane == 0) red[wid] = best;
        __syncthreads();
        if (tid == 0) {
          unsigned long long mx = red[0];
          for (int w = 1; w < 4; ++w)
            if (red[w] > mx) mx = red[w];
          bkey[0] = mx;
        }
        __syncthreads();
        const unsigned long long bk = bkey[0];
        const int pi = 255 - (int)((bk >> 8) & 255);
        const int pj = 255 - (int)(bk & 255);
        const int gi = gid[pi], gj = gid[pj];
        __syncthreads();
        if (gid[tid] == gi) gid[tid] = gj;
        __syncthreads();
      }
    }
  }
  __syncthreads();
  gidg[b * NTOK + tid] = gid[tid];
}

// ============ kernel 4: atomic-free epilogue (member lists + gather-sum) ============
// grid 128, block 256, small static LDS.
__global__ __launch_bounds__(256) void gm_epi(const float* __restrict__ V,
                                              float* __restrict__ OUT,
                                              const int* __restrict__ gidg) {
  __shared__ int gid[NTOK];
  __shared__ int cnt256[NTOK];
  __shared__ int scn[NTOK];
  __shared__ int rep[NOUT];
  __shared__ int wcnt[NTOK];
  __shared__ int slotStart[NOUT];
  __shared__ int mem[NTOK];

  const int tid = threadIdx.x;
  const int lane = tid & 63;
  const int wid = tid >> 6;
  const int b = blockIdx.x;

  gid[tid] = gidg[b * NTOK + tid];
  cnt256[tid] = 0;
  wcnt[tid] = 0;
  __syncthreads();
  atomicAdd(&cnt256[gid[tid]], 1);
  __syncthreads();

  if (wid == 0) {
    const int t4 = lane * 4;
    const int c0 = cnt256[t4 + 0] != 0, c1 = cnt256[t4 + 1] != 0,
              c2 = cnt256[t4 + 2] != 0, c3 = cnt256[t4 + 3] != 0;
    const int tot = c0 + c1 + c2 + c3;
    int run = tot;
#pragma unroll
    for (int off = 1; off < 64; off <<= 1) {
      int o = __shfl_up(run, off);
      if (lane >= off) run += o;
    }
    const int bs = run - tot;
    scn[t4 + 0] = bs + c0;
    scn[t4 + 1] = bs + c0 + c1;
    scn[t4 + 2] = bs + c0 + c1 + c2;
    scn[t4 + 3] = bs + tot;
  }
  __syncthreads();
  if (cnt256[tid]) rep[scn[tid] - 1] = tid;
  __syncthreads();

  if (wid == 0) {
    const int s0 = cnt256[rep[2 * lane]];
    const int s1 = cnt256[rep[2 * lane + 1]];
    const int pair = s0 + s1;
    int run = pair;
#pragma unroll
    for (int off = 1; off < 64; off <<= 1) {
      int o = __shfl_up(run, off);
      if (lane >= off) run += o;
    }
    const int base = run - pair;
    slotStart[2 * lane] = base;
    slotStart[2 * lane + 1] = base + s0;
  }
  __syncthreads();

  {
    const int g = gid[tid];
    const int pos = atomicAdd(&wcnt[g], 1);
    mem[slotStart[scn[g] - 1] + pos] = tid;
  }
  __syncthreads();

  {
    const int o = tid >> 1, h = tid & 1;
    const int g = rep[o];
    const int sz = cnt256[g];
    const int st = slotStart[o];
    float4 acc[8];
#pragma unroll
    for (int q = 0; q < 8; ++q) acc[q] = make_float4(0.f, 0.f, 0.f, 0.f);
    for (int m = 0; m < sz; ++m) {
      const int tok = mem[st + m];
      const float* vp = V + ((size_t)b * NTOK + tok) * DIM + h * 32;
#pragma unroll
      for (int q = 0; q < 8; ++q) {
        const float4 v4 = *reinterpret_cast<const float4*>(vp + q * 4);
        acc[q].x += v4.x; acc[q].y += v4.y; acc[q].z += v4.z; acc[q].w += v4.w;
      }
    }
    const float inv = 1.0f / (float)sz;
    float* op = OUT + (size_t)b * (NOUT * DIM) + (size_t)o * DIM + h * 32;
#pragma unroll
    for (int q = 0; q < 8; ++q) {
      float4 r;
      r.x = acc[q].x * inv; r.y = acc[q].y * inv;
      r.z = acc[q].z * inv; r.w = acc[q].w * inv;
      *reinterpret_cast<float4*>(op + q * 4) = r;
    }
  }
  float* outSz = OUT + (size_t)NB * NOUT * DIM + (size_t)b * NOUT;
  if (tid < NOUT) outSz[tid] = (float)cnt256[rep[tid]];
}

// ============ fused fallback (R7-style, known-passing) — only if ws too small ============
#define FPCAP 1024
#define FCAP 1024
#define SMEM_F 83584
__global__ __launch_bounds__(512) void gm_fused(const float* __restrict__ K,
                                                const float* __restrict__ V,
                                                float* __restrict__ OUT) {
  extern __shared__ char smem[];
  float* knT = (float*)smem;
  float* accO = (float*)smem;
  unsigned long long* keys = (unsigned long long*)(smem + 65536);
  unsigned* lpairs = (unsigned*)(smem + 73728);
  int* gid = (int*)(smem + 77824);
  int* cnt256 = (int*)(smem + 80896);
  int* scn = (int*)(smem + 81920);
  int* rep = (int*)(smem + 82944);
  unsigned long long* red = (unsigned long long*)(smem + 83456);
  unsigned long long* bkey = (unsigned long long*)(smem + 83520);
  int* misc = (int*)(smem + 83528);

  const int tid = threadIdx.x;
  const int lane = tid & 63;
  const int wid = tid >> 6;
  const int b = blockIdx.x;

  if (tid == 0) { misc[0] = 0; misc[1] = 0; }
  if (tid < NTOK) gid[tid] = tid;

  normalize_to_knT(K, knT, b, tid);
  __syncthreads();

  for (int t = tid; t < NTILES84; t += 512) {
    int ti, tj;
    tile84(t, ti, tj);
    const int i0 = ti * 8, j0 = tj * 4;
    float acc[8][4] = {};
#pragma unroll 4
    for (int d = 0; d < 64; ++d) {
      const float* row = knT + d * NTOK;
      const float4 a0 = *reinterpret_cast<const float4*>(row + i0);
      const float4 a1 = *reinterpret_cast<const float4*>(row + i0 + 4);
      const float4 bv = *reinterpret_cast<const float4*>(row + j0);
      const float aa[8] = {a0.x, a0.y, a0.z, a0.w, a1.x, a1.y, a1.z, a1.w};
      const float bb[4] = {bv.x, bv.y, bv.z, bv.w};
#pragma unroll
      for (int r = 0; r < 8; ++r)
#pragma unroll
        for (int c = 0; c < 4; ++c)
          acc[r][c] = fmaf(aa[r], bb[c], acc[r][c]);
    }
#pragma unroll
    for (int r = 0; r < 8; ++r)
#pragma unroll
      for (int c = 0; c < 4; ++c) {
        const int i = i0 + r, j = j0 + c;
        if (i < j && acc[r][c] >= SCREEN) {
          const int idx = atomicAdd(&misc[0], 1);
          if (idx < FPCAP) lpairs[idx] = (unsigned)((i << 8) | j);
        }
      }
  }
  __syncthreads();

  const int npRaw = misc[0];
  const int np = npRaw > FPCAP ? FPCAP : npRaw;
  const bool fullFB = (npRaw > FPCAP);
  for (int e = tid; e < np; e += 512) {
    const unsigned p = lpairs[e];
    const int i = (int)(p >> 8), j = (int)(p & 255u);
    double s = 0.0;
    for (int d = 0; d < 64; ++d)
      s = fma((double)knT[d * NTOK + i], (double)knT[d * NTOK + j], s);
    const float sf = (float)s;
    if (sf >= KAPPA) {
      const unsigned long long key =
          ((unsigned long long)mono_f32(sf) << 16) |
          (unsigned)(65535 - ((i << 8) | j));
      const int idx = atomicAdd(&misc[1], 1);
      keys[idx] = key;
    }
  }
  if (tid == 0) misc[3] = fullFB ? 0 : NMERGE;
  __syncthreads();
  const int nk = misc[1];

  {
    const int e0 = 2 * tid;
    unsigned long long v0 = (e0 + 0 < nk) ? keys[e0 + 0] : 0ULL;
    unsigned long long v1 = (e0 + 1 < nk) ? keys[e0 + 1] : 0ULL;
    for (int kk = 2; kk <= FCAP; kk <<= 1) {
      for (int jj = kk >> 1; jj > 0; jj >>= 1) {
        if (jj >= 128) {
          __syncthreads();
          keys[e0] = v0; keys[e0 + 1] = v1;
          __syncthreads();
          const int p0 = e0 ^ jj;
          const unsigned long long o0 = keys[p0], o1 = keys[p0 + 1];
          const bool km = ((e0 & kk) == 0) == ((e0 & jj) == 0);
          v0 = KEEP(v0, o0, km); v1 = KEEP(v1, o1, km);
        } else if (jj >= 2) {
          const int m = jj >> 1;
          const unsigned long long o0 = shflx64(v0, m), o1 = shflx64(v1, m);
          const bool km = ((e0 & kk) == 0) == ((e0 & jj) == 0);
          v0 = KEEP(v0, o0, km); v1 = KEEP(v1, o1, km);
        } else {
          const bool up = ((e0 & kk) == 0);
          CEX(v0, v1, up);
        }
      }
    }
    __syncthreads();
    keys[e0] = v0; keys[e0 + 1] = v1;
  }
  __syncthreads();

  if (misc[3] == NMERGE && wid == 0) {
    int rg0 = lane, rg1 = 64 + lane, rg2 = 128 + lane, rg3 = 192 + lane;
    int done = 0;
    for (int cursor = 0; cursor < nk && done < NMERGE; cursor += 64) {
      const int idx = cursor + lane;
      const unsigned long long key = (idx < nk) ? keys[idx] : 0ULL;
      const int pi = 255 - (int)((key >> 8) & 255);
      const int pj = 255 - (int)(key & 255);
      const int sli = pi & 63, ssi = pi >> 6;
      const int slj = pj & 63, ssj = pj >> 6;
      const int a0 = __shfl(rg0, sli), a1 = __shfl(rg1, sli),
                a2 = __shfl(rg2, sli), a3 = __shfl(rg3, sli);
      const int b0 = __shfl(rg0, slj), b1 = __shfl(rg1, slj),
                b2 = __shfl(rg2, slj), b3 = __shfl(rg3, slj);
      int gpi = (ssi == 0) ? a0 : (ssi == 1) ? a1 : (ssi == 2) ? a2 : a3;
      int gpj = (ssj == 0) ? b0 : (ssj == 1) ? b1 : (ssj == 2) ? b2 : b3;
      if (key == 0ULL) { gpi = 0; gpj = 0; }
      for (;;) {
        const unsigned long long mask = __ballot(gpi != gpj);
        if (!mask) break;
        const int f = __ffsll((long long)mask) - 1;
        const int gi = __shfl(gpi, f), gj = __shfl(gpj, f);
        if (lane == f) gpi = gpj;
        if (gpi == gi) gpi = gj;
        if (gpj == gi) gpj = gj;
        if (rg0 == gi) rg0 = gj;
        if (rg1 == gi) rg1 = gj;
        if (rg2 == gi) rg2 = gj;
        if (rg3 == gi) rg3 = gj;
        if (++done == NMERGE) break;
      }
    }
    gid[lane] = rg0; gid[64 + lane] = rg1;
    gid[128 + lane] = rg2; gid[192 + lane] = rg3;
    if (lane == 0) misc[3] = done;
  }
  __syncthreads();

  {
    const int start = misc[3];
    for (int mg = start; mg < NMERGE; ++mg) {
      unsigned long long best = 0ULL;
      const int p = tid >> 2, q = tid & 3;
      const int jA = 128 + p, jB = 127 - p;
      const int lenA = jA;
      const int s0 = q * 64, s1 = (q == 3) ? 255 : (q * 64 + 64);
      for (int e = s0; e < s1; ++e) {
        const int i = (e < lenA) ? e : (e - lenA);
        const int j = (e < lenA) ? jA : jB;
        if (gid[i] != gid[j]) {
          double s = 0.0;
          for (int d = 0; d < 64; ++d)
            s = fma((double)knT[d * NTOK + i], (double)knT[d * NTOK + j], s);
          const unsigned long long key =
              ((unsigned long long)mono_f32((float)s) << 16) |
              (unsigned)(65535 - ((i << 8) | j));
          if (key > best) best = key;
        }
      }
#pragma unroll
      for (int off = 32; off; off >>= 1) {
        unsigned long long o = __shfl_down(best, off);
        if (o > best) best = o;
      }
      if (lane == 0) red[wid] = best;
      __syncthreads();
      if (tid == 0) {
        unsigned long long mx = red[0];
        for (int w = 1; w < 8; ++w)
          if (red[w] > mx) mx = red[w];
        bkey[0] = mx;
      }
      __syncthreads();
      const unsigned long long bk = bkey[0];
      const int pi = 255 - (int)((bk >> 8) & 255);
      const int pj = 255 - (int)(bk & 255);
      const int gi = gid[pi], gj = gid[pj];
      __syncthreads();
      if (tid < NTOK && gid[tid] == gi) gid[tid] = gj;
      __syncthreads();
    }
  }
  __syncthreads();

  if (tid < NTOK) cnt256[tid] = 0;
  for (int e = tid; e < NOUT * DIM; e += 512) accO[e] = 0.0f;
  __syncthreads();
  if (tid < NTOK) atomicAdd(&cnt256[gid[tid]], 1);
  __syncthreads();
  if (wid == 0) {
    const int t4 = lane * 4;
    const int c0 = cnt256[t4 + 0] != 0, c1 = cnt256[t4 + 1] != 0,
              c2 = cnt256[t4 + 2] != 0, c3 = cnt256[t4 + 3] != 0;
    const int tot = c0 + c1 + c2 + c3;
    int run = tot;
#pragma unroll
    for (int off = 1; off < 64; off <<= 1) {
      int o = __shfl_up(run, off);
      if (lane >= off) run += o;
    }
    const int bs = run - tot;
    scn[t4 + 0] = bs + c0;
    scn[t4 + 1] = bs + c0 + c1;
    scn[t4 + 2] = bs + c0 + c1 + c2;
    scn[t4 + 3] = bs + tot;
  }
  __syncthreads();
  if (tid < NTOK && cnt256[tid]) rep[scn[tid] - 1] = tid;
  __syncthreads();

  {
    const int t = tid >> 1, h = tid & 1;
    const int slot = scn[gid[t]] - 1;
    const float* vp = V + ((size_t)b * NTOK + t) * DIM + h * 32;
    float* dst = accO + slot * DIM + h * 32;
#pragma unroll
    for (int q = 0; q < 8; ++q) {
      float4 v4 = *reinterpret_cast<const float4*>(vp + q * 4);
      atomicAdd(&dst[q * 4 + 0], v4.x);
      atomicAdd(&dst[q * 4 + 1], v4.y);
      atomicAdd(&dst[q * 4 + 2], v4.z);
      atomicAdd(&dst[q * 4 + 3], v4.w);
    }
  }
  __syncthreads();

  float* outMain = OUT + (size_t)b * (NOUT * DIM);
  for (int e = tid; e < NOUT * DIM; e += 512) {
    const int o = e >> 6;
    const float sz = (float)cnt256[rep[o]];
    outMain[e] = accO[e] / sz;
  }
  float* outSz = OUT + (size_t)NB * NOUT * DIM + (size_t)b * NOUT;
  for (int o = tid; o < NOUT; o += 512) outSz[o] = (float)cnt256[rep[o]];
}

extern "C" void kernel_launch(void* const* d_in, const int* in_sizes, int n_in,
                              void* d_out, int out_size, void* d_ws, size_t ws_size,
                              hipStream_t stream) {
  const float* K = (const float*)d_in[0];
  const float* V = (const float*)d_in[1];
  float* OUT = (float*)d_out;
  (void)in_sizes; (void)n_in; (void)out_size;

  // ws layout:
  //   gcnt[512] u32 @0 (4KB pad)
  //   knTg      @4096                (128*16384*4 = 8MB)
  //   gkeys     @4096+8MB            (128*1536*8 = 1.5MB)
  //   gidg      @4096+8MB+1.5MB      (128KB)
  const size_t knTBytes = (size_t)NB * KNT_ELEMS * sizeof(float);
  const size_t keysBytes = (size_t)NB * KTOT * sizeof(unsigned long long);
  const size_t need = 4096 + knTBytes + keysBytes + (size_t)NB * NTOK * sizeof(int);
  if (ws_size >= need) {
    unsigned* gcnt = (unsigned*)d_ws;
    float* knTg = (float*)((char*)d_ws + 4096);
    unsigned long long* gkeys = (unsigned long long*)((char*)d_ws + 4096 + knTBytes);
    int* gidg = (int*)((char*)d_ws + 4096 + knTBytes + keysBytes);
    hipFuncSetAttribute(reinterpret_cast<const void*>(gm_gram),
                        hipFuncAttributeMaxDynamicSharedMemorySize, SMEM_A);
    hipFuncSetAttribute(reinterpret_cast<const void*>(gm_walk),
                        hipFuncAttributeMaxDynamicSharedMemorySize, SMEM_K);
    gm_norm<<<dim3(NB), dim3(256), 0, stream>>>(K, knTg);
    gm_gram<<<dim3(NB * 4), dim3(256), SMEM_A, stream>>>(knTg, gcnt, gkeys);
    gm_sort<<<dim3(NB), dim3(256), 0, stream>>>(gcnt, gkeys);
    gm_walk<<<dim3(NB), dim3(256), SMEM_K, stream>>>(knTg, gcnt, gkeys, gidg);
    gm_epi<<<dim3(NB), dim3(256), 0, stream>>>(V, OUT, gidg);
  } else {
    hipFuncSetAttribute(reinterpret_cast<const void*>(gm_fused),
                        hipFuncAttributeMaxDynamicSharedMemorySize, SMEM_F);
    gm_fused<<<dim3(NB), dim3(512), SMEM_F, stream>>>(K, V, OUT);
  }
}

// Round 13
// 93.143 us; speedup vs baseline: 1.1483x; 1.1483x over previous
//
#include <hip/hip_runtime.h>
#include <stdint.h>

#define NTOK 256
#define NOUT 128
#define DIM 64
#define NB 128
#define NSEG 4
#define LCAP 384          // keys per segment (expected ~224, +10.6 sigma)
#define KTOT 1536         // NSEG * LCAP
#define WCAP 1024         // fast-path sort capacity (empirically >= all batches)
#define PCAPA 512
#define NMERGE 128
#define KAPPA 0.24f
#define SCREEN 0.2395f
#define NTILES84 1056
#define TILES_PER_SUB84 264
#define KNT_ELEMS (DIM * NTOK)   // 16384 floats = 64KB

__device__ __forceinline__ unsigned mono_f32(float s) {
  unsigned u = __float_as_uint(s);
  return (u & 0x80000000u) ? ~u : (u | 0x80000000u);
}

__device__ __forceinline__ unsigned long long shflx64(unsigned long long x, int m) {
  unsigned lo = (unsigned)x, hi = (unsigned)(x >> 32);
  lo = __shfl_xor(lo, m);
  hi = __shfl_xor(hi, m);
  return ((unsigned long long)hi << 32) | lo;
}

// invert T -> (ti, tj) on the 8x4 tile grid: ti in [0,32), tj in [2*ti, 64)
__device__ __forceinline__ void tile84(int T, int& tio, int& tjo) {
  float tf = (65.0f - sqrtf(4225.0f - 4.0f * (float)T)) * 0.5f;
  int t = (int)tf;
  if (t < 0) t = 0;
  if (t > 31) t = 31;
  while (t < 31 && 65 * (t + 1) - (t + 1) * (t + 1) <= T) ++t;
  while (t > 0 && 65 * t - t * t > T) --t;
  tio = t;
  tjo = 2 * t + (T - (65 * t - t * t));
}

#define CEX(a, b, up)                         \
  do {                                        \
    unsigned long long _a = (a), _b = (b);    \
    bool _sw = (up) ? (_a < _b) : (_a > _b);  \
    if (_sw) { (a) = _b; (b) = _a; }          \
  } while (0)

#define KEEP(v, o, km) ((km) ? ((v) > (o) ? (v) : (o)) : ((v) < (o) ? (v) : (o)))

// ---- per-token normalize chain (bit-identical to all prior rounds) ----
__device__ __forceinline__ void norm_vals(const float* __restrict__ kp,
                                          float* __restrict__ vals,
                                          double& nrm) {
  double s0 = 0.0, s1 = 0.0;
#pragma unroll
  for (int q = 0; q < 8; ++q) {
    float4 v4 = *reinterpret_cast<const float4*>(kp + q * 4);
    vals[q * 4 + 0] = v4.x; vals[q * 4 + 1] = v4.y;
    vals[q * 4 + 2] = v4.z; vals[q * 4 + 3] = v4.w;
    s0 += (double)v4.x * v4.x + (double)v4.y * v4.y +
          (double)v4.z * v4.z + (double)v4.w * v4.w;
  }
#pragma unroll
  for (int q = 8; q < 16; ++q) {
    float4 v4 = *reinterpret_cast<const float4*>(kp + q * 4);
    vals[q * 4 + 0] = v4.x; vals[q * 4 + 1] = v4.y;
    vals[q * 4 + 2] = v4.z; vals[q * 4 + 3] = v4.w;
    s1 += (double)v4.x * v4.x + (double)v4.y * v4.y +
          (double)v4.z * v4.z + (double)v4.w * v4.w;
  }
  nrm = sqrt(s0 + s1);
}

// ---- 512-thread normalize (gm_fused fallback only) ----
__device__ __forceinline__ void normalize_to_knT(const float* __restrict__ K,
                                                 float* __restrict__ knT,
                                                 int b, int tid) {
  const int t = tid >> 1, h = tid & 1;
  const float* kp = K + ((size_t)b * NTOK + t) * DIM + h * 32;
  double ss = 0.0;
  float vals[32];
#pragma unroll
  for (int q = 0; q < 8; ++q) {
    float4 v4 = *reinterpret_cast<const float4*>(kp + q * 4);
    vals[q * 4 + 0] = v4.x; vals[q * 4 + 1] = v4.y;
    vals[q * 4 + 2] = v4.z; vals[q * 4 + 3] = v4.w;
    ss += (double)v4.x * v4.x + (double)v4.y * v4.y +
          (double)v4.z * v4.z + (double)v4.w * v4.w;
  }
  double other = __shfl_xor(ss, 1);
  double nrm = sqrt(ss + other);
#pragma unroll
  for (int q = 0; q < 32; ++q)
    knT[(h * 32 + q) * NTOK + t] = (float)((double)vals[q] / nrm);
}

// ============ kernel 0: normalize once per batch -> knTg[b][d][t] ============
__global__ __launch_bounds__(256) void gm_norm(const float* __restrict__ K,
                                               float* __restrict__ knTg) {
  const int t = threadIdx.x;
  const int b = blockIdx.x;
  const float* kp = K + ((size_t)b * NTOK + t) * DIM;
  float vals[64];
  double nrm;
  norm_vals(kp, vals, nrm);
  float* dst = knTg + (size_t)b * KNT_ELEMS;
#pragma unroll
  for (int d = 0; d < 64; ++d)
    dst[d * NTOK + t] = (float)((double)vals[d] / nrm);
}

// ============ kernel 1: gram screen + exact f64 + fixed-segment flush ============
// grid 512 (4 WGs/batch), block 256.
// LDS: knT 64KB @0, lpairs 2KB @65536, lkeys 3KB @67584, lmisc @70656
#define SMEM_A 70672
__global__ __launch_bounds__(256) void gm_gram(const float* __restrict__ knTg,
                                               unsigned* __restrict__ gcnt,
                                               unsigned long long* __restrict__ gkeys) {
  extern __shared__ char smem[];
  float* knT = (float*)smem;
  unsigned* lpairs = (unsigned*)(smem + 65536);
  unsigned long long* lkeys = (unsigned long long*)(smem + 67584);
  int* lmisc = (int*)(smem + 70656);

  const int tid = threadIdx.x;
  const int b = blockIdx.x >> 2, sub = blockIdx.x & 3;

  if (tid == 0) { lmisc[0] = 0; lmisc[1] = 0; }
  {
    const float4* src = reinterpret_cast<const float4*>(knTg + (size_t)b * KNT_ELEMS);
    float4* dst = reinterpret_cast<float4*>(knT);
#pragma unroll
    for (int e = 0; e < KNT_ELEMS / 4 / 256; ++e)
      dst[e * 256 + tid] = src[e * 256 + tid];
  }
  __syncthreads();

  const int base = sub * TILES_PER_SUB84;
  for (int t = tid; t < TILES_PER_SUB84; t += 256) {
    int ti, tj;
    tile84(base + t, ti, tj);
    const int i0 = ti * 8, j0 = tj * 4;

    float acc[8][4] = {};
#pragma unroll 4
    for (int d = 0; d < 64; ++d) {
      const float* row = knT + d * NTOK;
      const float4 a0 = *reinterpret_cast<const float4*>(row + i0);
      const float4 a1 = *reinterpret_cast<const float4*>(row + i0 + 4);
      const float4 bv = *reinterpret_cast<const float4*>(row + j0);
      const float aa[8] = {a0.x, a0.y, a0.z, a0.w, a1.x, a1.y, a1.z, a1.w};
      const float bb[4] = {bv.x, bv.y, bv.z, bv.w};
#pragma unroll
      for (int r = 0; r < 8; ++r)
#pragma unroll
        for (int c = 0; c < 4; ++c)
          acc[r][c] = fmaf(aa[r], bb[c], acc[r][c]);
    }
#pragma unroll
    for (int r = 0; r < 8; ++r)
#pragma unroll
      for (int c = 0; c < 4; ++c) {
        const int i = i0 + r, j = j0 + c;
        if (i < j && acc[r][c] >= SCREEN) {
          const int idx = atomicAdd(&lmisc[0], 1);
          if (idx < PCAPA) lpairs[idx] = (unsigned)((i << 8) | j);
        }
      }
  }
  __syncthreads();

  const int npRaw = lmisc[0];
  const int np = npRaw > PCAPA ? PCAPA : npRaw;
  for (int e = tid; e < np; e += 256) {
    const unsigned p = lpairs[e];
    const int i = (int)(p >> 8), j = (int)(p & 255u);
    double s = 0.0;
    for (int d = 0; d < 64; ++d)
      s = fma((double)knT[d * NTOK + i], (double)knT[d * NTOK + j], s);
    const float sf = (float)s;
    if (sf >= KAPPA) {
      const unsigned long long key =
          ((unsigned long long)mono_f32(sf) << 16) |
          (unsigned)(65535 - ((i << 8) | j));
      const int idx = atomicAdd(&lmisc[1], 1);
      if (idx < LCAP) lkeys[idx] = key;
    }
  }
  __syncthreads();

  const int nkRaw = lmisc[1];
  if (tid == 0)
    gcnt[NSEG * b + sub] =
        (npRaw > PCAPA || nkRaw > LCAP) ? 0x7FFFFFFFu : (unsigned)nkRaw;
  const int nk = nkRaw > LCAP ? LCAP : nkRaw;
  unsigned long long* seg = gkeys + (size_t)b * KTOT + (size_t)sub * LCAP;
  for (int e = tid; e < nk; e += 256) seg[e] = lkeys[e];
}

// ---- segment counts -> clamped sizes + prefix + flags ----
__device__ __forceinline__ void seg_info(const unsigned* __restrict__ gcnt, int b,
                                         int n[NSEG], int offs[NSEG], int& cntC,
                                         bool& fast) {
  bool ovf = false;
  int run = 0;
#pragma unroll
  for (int s = 0; s < NSEG; ++s) {
    const unsigned m = gcnt[NSEG * b + s];
    if (m > LCAP) ovf = true;
    n[s] = m > LCAP ? LCAP : (int)m;
    offs[s] = run;
    run += n[s];
  }
  cntC = run;
  fast = !ovf && (cntC <= WCAP);
}

// ============ kernel 2: sort + walk + fallback + epilogue (fused, R4/R10 shape) ============
// grid 128, block 256, dynamic LDS.
// LDS: knT(fallback)/accO(epilogue) alias 64KB @0, keys 8KB @65536,
//      gid @73728, cnt256 @74752, scn @75776, rep @76800,
//      misc @77312, red @77328, bkey @77392
#define SMEM_S 77400
__global__ __launch_bounds__(256) void gm_swe(const float* __restrict__ knTg,
                                              const float* __restrict__ V,
                                              float* __restrict__ OUT,
                                              const unsigned* __restrict__ gcnt,
                                              const unsigned long long* __restrict__ gkeys) {
  extern __shared__ char smem[];
  float* knT = (float*)smem;          // live only during fallback
  float* accO = (float*)smem;         // live only during epilogue
  unsigned long long* keys = (unsigned long long*)(smem + 65536);
  int* gid = (int*)(smem + 73728);
  int* cnt256 = (int*)(smem + 74752);
  int* scn = (int*)(smem + 75776);
  int* rep = (int*)(smem + 76800);
  int* misc = (int*)(smem + 77312);
  unsigned long long* red = (unsigned long long*)(smem + 77328);
  unsigned long long* bkey = (unsigned long long*)(smem + 77392);

  const int tid = threadIdx.x;
  const int lane = tid & 63;
  const int wid = tid >> 6;
  const int b = blockIdx.x;

  int n[NSEG], offs[NSEG], cntC;
  bool fast;
  seg_info(gcnt, b, n, offs, cntC, fast);

  if (tid == 0) misc[3] = fast ? NMERGE : 0;
  gid[tid] = tid;

  // packed load: dst slot -> (segment, offset); zeros beyond cntC
  {
    const unsigned long long* gk = gkeys + (size_t)b * KTOT;
    for (int dst = tid; dst < WCAP; dst += 256) {
      unsigned long long v = 0ULL;
      if (fast && dst < cntC) {
        int seg = 0, base = 0;
#pragma unroll
        for (int s = 1; s < NSEG; ++s)
          if (dst >= offs[s]) { seg = s; base = offs[s]; }
        v = gk[seg * LCAP + (dst - base)];
      }
      keys[dst] = v;
    }
  }
  __syncthreads();

  // ---- bitonic sort (descending) of 1024, 4 keys/thread ----
  {
    const int e0 = 4 * tid;
    unsigned long long v0 = keys[e0], v1 = keys[e0 + 1],
                       v2 = keys[e0 + 2], v3 = keys[e0 + 3];
    for (int kk = 2; kk <= WCAP; kk <<= 1) {
      for (int jj = kk >> 1; jj > 0; jj >>= 1) {
        if (jj >= 256) {
          __syncthreads();
          keys[e0] = v0; keys[e0 + 1] = v1; keys[e0 + 2] = v2; keys[e0 + 3] = v3;
          __syncthreads();
          const int p0 = e0 ^ jj;
          unsigned long long o0 = keys[p0], o1 = keys[p0 + 1],
                             o2 = keys[p0 + 2], o3 = keys[p0 + 3];
          const bool km = ((e0 & kk) == 0) == ((e0 & jj) == 0);
          v0 = KEEP(v0, o0, km); v1 = KEEP(v1, o1, km);
          v2 = KEEP(v2, o2, km); v3 = KEEP(v3, o3, km);
        } else if (jj >= 4) {
          const int m = jj >> 2;
          unsigned long long o0 = shflx64(v0, m), o1 = shflx64(v1, m),
                             o2 = shflx64(v2, m), o3 = shflx64(v3, m);
          const bool km = ((e0 & kk) == 0) == ((e0 & jj) == 0);
          v0 = KEEP(v0, o0, km); v1 = KEEP(v1, o1, km);
          v2 = KEEP(v2, o2, km); v3 = KEEP(v3, o3, km);
        } else if (jj == 2) {
          const bool up = ((e0 & kk) == 0);
          CEX(v0, v2, up); CEX(v1, v3, up);
        } else {
          bool up0, up1;
          if (kk == 2) { up0 = true; up1 = false; }
          else { up0 = up1 = ((e0 & kk) == 0); }
          CEX(v0, v1, up0); CEX(v2, v3, up1);
        }
      }
    }
    __syncthreads();
    keys[e0] = v0; keys[e0 + 1] = v1; keys[e0 + 2] = v2; keys[e0 + 3] = v3;
  }
  __syncthreads();

  // ---- serial-shfl walk (wave 0), gid entirely in registers ----
  if (fast && wid == 0) {
    int rg0 = lane, rg1 = 64 + lane, rg2 = 128 + lane, rg3 = 192 + lane;
    int done = 0;
    for (int cursor = 0; cursor < cntC && done < NMERGE; cursor += 64) {
      const int idx = cursor + lane;
      const unsigned long long key = (idx < cntC) ? keys[idx] : 0ULL;
      const int pi = 255 - (int)((key >> 8) & 255);
      const int pj = 255 - (int)(key & 255);
      const int sli = pi & 63, ssi = pi >> 6;
      const int slj = pj & 63, ssj = pj >> 6;
      const int a0 = __shfl(rg0, sli), a1 = __shfl(rg1, sli),
                a2 = __shfl(rg2, sli), a3 = __shfl(rg3, sli);
      const int b0 = __shfl(rg0, slj), b1 = __shfl(rg1, slj),
                b2 = __shfl(rg2, slj), b3 = __shfl(rg3, slj);
      int gpi = (ssi == 0) ? a0 : (ssi == 1) ? a1 : (ssi == 2) ? a2 : a3;
      int gpj = (ssj == 0) ? b0 : (ssj == 1) ? b1 : (ssj == 2) ? b2 : b3;
      if (key == 0ULL) { gpi = 0; gpj = 0; }
      for (;;) {
        const unsigned long long mask = __ballot(gpi != gpj);
        if (!mask) break;
        const int f = __ffsll((long long)mask) - 1;
        const int gij = __shfl((gpi << 8) | gpj, f);
        const int gi = gij >> 8, gj = gij & 255;
        if (gpi == gi) gpi = gj;
        if (gpj == gi) gpj = gj;
        if (rg0 == gi) rg0 = gj;
        if (rg1 == gi) rg1 = gj;
        if (rg2 == gi) rg2 = gj;
        if (rg3 == gi) rg3 = gj;
        if (++done == NMERGE) break;
      }
    }
    gid[lane] = rg0; gid[64 + lane] = rg1;
    gid[128 + lane] = rg2; gid[192 + lane] = rg3;
    if (lane == 0) misc[3] = done;
  }
  __syncthreads();

  // ---- cheap exact fallback: knTg -> LDS, argmax per remaining merge ----
  {
    const int start = misc[3];
    if (start < NMERGE) {
      {
        const float4* src = reinterpret_cast<const float4*>(knTg + (size_t)b * KNT_ELEMS);
        float4* dst = reinterpret_cast<float4*>(knT);
#pragma unroll
        for (int e = 0; e < KNT_ELEMS / 4 / 256; ++e)
          dst[e * 256 + tid] = src[e * 256 + tid];
      }
      __syncthreads();
      for (int mg = start; mg < NMERGE; ++mg) {
        unsigned long long best = 0ULL;
        const int p = tid >> 1, q = tid & 1;
        const int jA = 128 + p, jB = 127 - p;
        const int lenA = jA;
        const int s0 = q * 128, s1 = (q == 1) ? 255 : 128;
        for (int e = s0; e < s1; ++e) {
          const int i = (e < lenA) ? e : (e - lenA);
          const int j = (e < lenA) ? jA : jB;
          if (gid[i] != gid[j]) {
            double s = 0.0;
            for (int d = 0; d < 64; ++d)
              s = fma((double)knT[d * NTOK + i], (double)knT[d * NTOK + j], s);
            const unsigned long long key =
                ((unsigned long long)mono_f32((float)s) << 16) |
                (unsigned)(65535 - ((i << 8) | j));
            if (key > best) best = key;
          }
        }
#pragma unroll
        for (int off = 32; off; off >>= 1) {
          unsigned long long o = __shfl_down(best, off);
          if (o > best) best = o;
        }
        if (lane == 0) red[wid] = best;
        __syncthreads();
        if (tid == 0) {
          unsigned long long mx = red[0];
          for (int w = 1; w < 4; ++w)
            if (red[w] > mx) mx = red[w];
          bkey[0] = mx;
        }
        __syncthreads();
        const unsigned long long bk = bkey[0];
        const int pi = 255 - (int)((bk >> 8) & 255);
        const int pj = 255 - (int)(bk & 255);
        const int gi = gid[pi], gj = gid[pj];
        __syncthreads();
        if (gid[tid] == gi) gid[tid] = gj;
        __syncthreads();
      }
    }
  }
  __syncthreads();
  // knT dead from here; accO (alias) becomes live.

  // ---- sizes + single-wave prefix scan + slots (R10-proven) ----
  cnt256[tid] = 0;
  __syncthreads();
  atomicAdd(&cnt256[gid[tid]], 1);
  __syncthreads();
  if (wid == 0) {
    const int t4 = lane * 4;
    const int c0 = cnt256[t4 + 0] != 0, c1 = cnt256[t4 + 1] != 0,
              c2 = cnt256[t4 + 2] != 0, c3 = cnt256[t4 + 3] != 0;
    const int tot = c0 + c1 + c2 + c3;
    int run = tot;
#pragma unroll
    for (int off = 1; off < 64; off <<= 1) {
      int o = __shfl_up(run, off);
      if (lane >= off) run += o;
    }
    const int bs = run - tot;
    scn[t4 + 0] = bs + c0;
    scn[t4 + 1] = bs + c0 + c1;
    scn[t4 + 2] = bs + c0 + c1 + c2;
    scn[t4 + 3] = bs + tot;
  }
  __syncthreads();
  if (cnt256[tid]) rep[scn[tid] - 1] = tid;
  // zero accO AFTER rep is built (accO aliases knT which is now dead)
  __syncthreads();
  for (int e = tid; e < NOUT * DIM; e += 256) accO[e] = 0.0f;
  __syncthreads();

  // ---- accumulate V into slots: thread = token, coalesced reads + LDS atomics ----
  {
    const int slot = scn[gid[tid]] - 1;
    const float* vp = V + ((size_t)b * NTOK + tid) * DIM;
    float* dst = accO + slot * DIM;
#pragma unroll
    for (int q = 0; q < 16; ++q) {
      float4 v4 = *reinterpret_cast<const float4*>(vp + q * 4);
      atomicAdd(&dst[q * 4 + 0], v4.x);
      atomicAdd(&dst[q * 4 + 1], v4.y);
      atomicAdd(&dst[q * 4 + 2], v4.z);
      atomicAdd(&dst[q * 4 + 3], v4.w);
    }
  }
  __syncthreads();

  // ---- write outputs ----
  float* outMain = OUT + (size_t)b * (NOUT * DIM);
  for (int e = tid; e < NOUT * DIM; e += 256) {
    const int o = e >> 6;
    const float sz = (float)cnt256[rep[o]];
    outMain[e] = accO[e] / sz;
  }
  float* outSz = OUT + (size_t)NB * NOUT * DIM + (size_t)b * NOUT;
  if (tid < NOUT) outSz[tid] = (float)cnt256[rep[tid]];
}

// ============ fused fallback (R7-style, known-passing) — only if ws too small ============
#define FPCAP 1024
#define FCAP 1024
#define SMEM_F 83584
__global__ __launch_bounds__(512) void gm_fused(const float* __restrict__ K,
                                                const float* __restrict__ V,
                                                float* __restrict__ OUT) {
  extern __shared__ char smem[];
  float* knT = (float*)smem;
  float* accO = (float*)smem;
  unsigned long long* keys = (unsigned long long*)(smem + 65536);
  unsigned* lpairs = (unsigned*)(smem + 73728);
  int* gid = (int*)(smem + 77824);
  int* cnt256 = (int*)(smem + 80896);
  int* scn = (int*)(smem + 81920);
  int* rep = (int*)(smem + 82944);
  unsigned long long* red = (unsigned long long*)(smem + 83456);
  unsigned long long* bkey = (unsigned long long*)(smem + 83520);
  int* misc = (int*)(smem + 83528);

  const int tid = threadIdx.x;
  const int lane = tid & 63;
  const int wid = tid >> 6;
  const int b = blockIdx.x;

  if (tid == 0) { misc[0] = 0; misc[1] = 0; }
  if (tid < NTOK) gid[tid] = tid;

  normalize_to_knT(K, knT, b, tid);
  __syncthreads();

  for (int t = tid; t < NTILES84; t += 512) {
    int ti, tj;
    tile84(t, ti, tj);
    const int i0 = ti * 8, j0 = tj * 4;
    float acc[8][4] = {};
#pragma unroll 4
    for (int d = 0; d < 64; ++d) {
      const float* row = knT + d * NTOK;
      const float4 a0 = *reinterpret_cast<const float4*>(row + i0);
      const float4 a1 = *reinterpret_cast<const float4*>(row + i0 + 4);
      const float4 bv = *reinterpret_cast<const float4*>(row + j0);
      const float aa[8] = {a0.x, a0.y, a0.z, a0.w, a1.x, a1.y, a1.z, a1.w};
      const float bb[4] = {bv.x, bv.y, bv.z, bv.w};
#pragma unroll
      for (int r = 0; r < 8; ++r)
#pragma unroll
        for (int c = 0; c < 4; ++c)
          acc[r][c] = fmaf(aa[r], bb[c], acc[r][c]);
    }
#pragma unroll
    for (int r = 0; r < 8; ++r)
#pragma unroll
      for (int c = 0; c < 4; ++c) {
        const int i = i0 + r, j = j0 + c;
        if (i < j && acc[r][c] >= SCREEN) {
          const int idx = atomicAdd(&misc[0], 1);
          if (idx < FPCAP) lpairs[idx] = (unsigned)((i << 8) | j);
        }
      }
  }
  __syncthreads();

  const int npRaw = misc[0];
  const int np = npRaw > FPCAP ? FPCAP : npRaw;
  const bool fullFB = (npRaw > FPCAP);
  for (int e = tid; e < np; e += 512) {
    const unsigned p = lpairs[e];
    const int i = (int)(p >> 8), j = (int)(p & 255u);
    double s = 0.0;
    for (int d = 0; d < 64; ++d)
      s = fma((double)knT[d * NTOK + i], (double)knT[d * NTOK + j], s);
    const float sf = (float)s;
    if (sf >= KAPPA) {
      const unsigned long long key =
          ((unsigned long long)mono_f32(sf) << 16) |
          (unsigned)(65535 - ((i << 8) | j));
      const int idx = atomicAdd(&misc[1], 1);
      keys[idx] = key;
    }
  }
  if (tid == 0) misc[3] = fullFB ? 0 : NMERGE;
  __syncthreads();
  const int nk = misc[1];

  {
    const int e0 = 2 * tid;
    unsigned long long v0 = (e0 + 0 < nk) ? keys[e0 + 0] : 0ULL;
    unsigned long long v1 = (e0 + 1 < nk) ? keys[e0 + 1] : 0ULL;
    for (int kk = 2; kk <= FCAP; kk <<= 1) {
      for (int jj = kk >> 1; jj > 0; jj >>= 1) {
        if (jj >= 128) {
          __syncthreads();
          keys[e0] = v0; keys[e0 + 1] = v1;
          __syncthreads();
          const int p0 = e0 ^ jj;
          const unsigned long long o0 = keys[p0], o1 = keys[p0 + 1];
          const bool km = ((e0 & kk) == 0) == ((e0 & jj) == 0);
          v0 = KEEP(v0, o0, km); v1 = KEEP(v1, o1, km);
        } else if (jj >= 2) {
          const int m = jj >> 1;
          const unsigned long long o0 = shflx64(v0, m), o1 = shflx64(v1, m);
          const bool km = ((e0 & kk) == 0) == ((e0 & jj) == 0);
          v0 = KEEP(v0, o0, km); v1 = KEEP(v1, o1, km);
        } else {
          const bool up = ((e0 & kk) == 0);
          CEX(v0, v1, up);
        }
      }
    }
    __syncthreads();
    keys[e0] = v0; keys[e0 + 1] = v1;
  }
  __syncthreads();

  if (misc[3] == NMERGE && wid == 0) {
    int rg0 = lane, rg1 = 64 + lane, rg2 = 128 + lane, rg3 = 192 + lane;
    int done = 0;
    for (int cursor = 0; cursor < nk && done < NMERGE; cursor += 64) {
      const int idx = cursor + lane;
      const unsigned long long key = (idx < nk) ? keys[idx] : 0ULL;
      const int pi = 255 - (int)((key >> 8) & 255);
      const int pj = 255 - (int)(key & 255);
      const int sli = pi & 63, ssi = pi >> 6;
      const int slj = pj & 63, ssj = pj >> 6;
      const int a0 = __shfl(rg0, sli), a1 = __shfl(rg1, sli),
                a2 = __shfl(rg2, sli), a3 = __shfl(rg3, sli);
      const int b0 = __shfl(rg0, slj), b1 = __shfl(rg1, slj),
                b2 = __shfl(rg2, slj), b3 = __shfl(rg3, slj);
      int gpi = (ssi == 0) ? a0 : (ssi == 1) ? a1 : (ssi == 2) ? a2 : a3;
      int gpj = (ssj == 0) ? b0 : (ssj == 1) ? b1 : (ssj == 2) ? b2 : b3;
      if (key == 0ULL) { gpi = 0; gpj = 0; }
      for (;;) {
        const unsigned long long mask = __ballot(gpi != gpj);
        if (!mask) break;
        const int f = __ffsll((long long)mask) - 1;
        const int gi = __shfl(gpi, f), gj = __shfl(gpj, f);
        if (lane == f) gpi = gpj;
        if (gpi == gi) gpi = gj;
        if (gpj == gi) gpj = gj;
        if (rg0 == gi) rg0 = gj;
        if (rg1 == gi) rg1 = gj;
        if (rg2 == gi) rg2 = gj;
        if (rg3 == gi) rg3 = gj;
        if (++done == NMERGE) break;
      }
    }
    gid[lane] = rg0; gid[64 + lane] = rg1;
    gid[128 + lane] = rg2; gid[192 + lane] = rg3;
    if (lane == 0) misc[3] = done;
  }
  __syncthreads();

  {
    const int start = misc[3];
    for (int mg = start; mg < NMERGE; ++mg) {
      unsigned long long best = 0ULL;
      const int p = tid >> 2, q = tid & 3;
      const int jA = 128 + p, jB = 127 - p;
      const int lenA = jA;
      const int s0 = q * 64, s1 = (q == 3) ? 255 : (q * 64 + 64);
      for (int e = s0; e < s1; ++e) {
        const int i = (e < lenA) ? e : (e - lenA);
        const int j = (e < lenA) ? jA : jB;
        if (gid[i] != gid[j]) {
          double s = 0.0;
          for (int d = 0; d < 64; ++d)
            s = fma((double)knT[d * NTOK + i], (double)knT[d * NTOK + j], s);
          const unsigned long long key =
              ((unsigned long long)mono_f32((float)s) << 16) |
              (unsigned)(65535 - ((i << 8) | j));
          if (key > best) best = key;
        }
      }
#pragma unroll
      for (int off = 32; off; off >>= 1) {
        unsigned long long o = __shfl_down(best, off);
        if (o > best) best = o;
      }
      if (lane == 0) red[wid] = best;
      __syncthreads();
      if (tid == 0) {
        unsigned long long mx = red[0];
        for (int w = 1; w < 8; ++w)
          if (red[w] > mx) mx = red[w];
        bkey[0] = mx;
      }
      __syncthreads();
      const unsigned long long bk = bkey[0];
      const int pi = 255 - (int)((bk >> 8) & 255);
      const int pj = 255 - (int)(bk & 255);
      const int gi = gid[pi], gj = gid[pj];
      __syncthreads();
      if (tid < NTOK && gid[tid] == gi) gid[tid] = gj;
      __syncthreads();
    }
  }
  __syncthreads();

  if (tid < NTOK) cnt256[tid] = 0;
  for (int e = tid; e < NOUT * DIM; e += 512) accO[e] = 0.0f;
  __syncthreads();
  if (tid < NTOK) atomicAdd(&cnt256[gid[tid]], 1);
  __syncthreads();
  if (wid == 0) {
    const int t4 = lane * 4;
    const int c0 = cnt256[t4 + 0] != 0, c1 = cnt256[t4 + 1] != 0,
              c2 = cnt256[t4 + 2] != 0, c3 = cnt256[t4 + 3] != 0;
    const int tot = c0 + c1 + c2 + c3;
    int run = tot;
#pragma unroll
    for (int off = 1; off < 64; off <<= 1) {
      int o = __shfl_up(run, off);
      if (lane >= off) run += o;
    }
    const int bs = run - tot;
    scn[t4 + 0] = bs + c0;
    scn[t4 + 1] = bs + c0 + c1;
    scn[t4 + 2] = bs + c0 + c1 + c2;
    scn[t4 + 3] = bs + tot;
  }
  __syncthreads();
  if (tid < NTOK && cnt256[tid]) rep[scn[tid] - 1] = tid;
  __syncthreads();

  {
    const int t = tid >> 1, h = tid & 1;
    const int slot = scn[gid[t]] - 1;
    const float* vp = V + ((size_t)b * NTOK + t) * DIM + h * 32;
    float* dst = accO + slot * DIM + h * 32;
#pragma unroll
    for (int q = 0; q < 8; ++q) {
      float4 v4 = *reinterpret_cast<const float4*>(vp + q * 4);
      atomicAdd(&dst[q * 4 + 0], v4.x);
      atomicAdd(&dst[q * 4 + 1], v4.y);
      atomicAdd(&dst[q * 4 + 2], v4.z);
      atomicAdd(&dst[q * 4 + 3], v4.w);
    }
  }
  __syncthreads();

  float* outMain = OUT + (size_t)b * (NOUT * DIM);
  for (int e = tid; e < NOUT * DIM; e += 512) {
    const int o = e >> 6;
    const float sz = (float)cnt256[rep[o]];
    outMain[e] = accO[e] / sz;
  }
  float* outSz = OUT + (size_t)NB * NOUT * DIM + (size_t)b * NOUT;
  for (int o = tid; o < NOUT; o += 512) outSz[o] = (float)cnt256[rep[o]];
}

extern "C" void kernel_launch(void* const* d_in, const int* in_sizes, int n_in,
                              void* d_out, int out_size, void* d_ws, size_t ws_size,
                              hipStream_t stream) {
  const float* K = (const float*)d_in[0];
  const float* V = (const float*)d_in[1];
  float* OUT = (float*)d_out;
  (void)in_sizes; (void)n_in; (void)out_size;

  // ws layout:
  //   gcnt[512] u32 @0 (4KB pad)
  //   knTg      @4096                (128*16384*4 = 8MB)
  //   gkeys     @4096+8MB            (128*1536*8 = 1.5MB)
  const size_t knTBytes = (size_t)NB * KNT_ELEMS * sizeof(float);
  const size_t keysBytes = (size_t)NB * KTOT * sizeof(unsigned long long);
  const size_t need = 4096 + knTBytes + keysBytes;
  if (ws_size >= need) {
    unsigned* gcnt = (unsigned*)d_ws;
    float* knTg = (float*)((char*)d_ws + 4096);
    unsigned long long* gkeys = (unsigned long long*)((char*)d_ws + 4096 + knTBytes);
    hipFuncSetAttribute(reinterpret_cast<const void*>(gm_gram),
                        hipFuncAttributeMaxDynamicSharedMemorySize, SMEM_A);
    hipFuncSetAttribute(reinterpret_cast<const void*>(gm_swe),
                        hipFuncAttributeMaxDynamicSharedMemorySize, SMEM_S);
    gm_norm<<<dim3(NB), dim3(256), 0, stream>>>(K, knTg);
    gm_gram<<<dim3(NB * 4), dim3(256), SMEM_A, stream>>>(knTg, gcnt, gkeys);
    gm_swe<<<dim3(NB), dim3(256), SMEM_S, stream>>>(knTg, V, OUT, gcnt, gkeys);
  } else {
    hipFuncSetAttribute(reinterpret_cast<const void*>(gm_fused),
                        hipFuncAttributeMaxDynamicSharedMemorySize, SMEM_F);
    gm_fused<<<dim3(NB), dim3(512), SMEM_F, stream>>>(K, V, OUT);
  }
}

// Round 14
// 84.953 us; speedup vs baseline: 1.2590x; 1.0964x over previous
//
#include <hip/hip_runtime.h>
#include <stdint.h>

#define NTOK 256
#define NOUT 128
#define DIM 64
#define NB 128
#define CAP 1024
#define PCAP 1024
#define NMERGE 128
#define KAPPA 0.24f
#define SCREEN 0.2395f
#define NTILES84 1056

// LDS layout (bytes):
//   knT    [64][256] f32 : 65536 @ 0       (aliased by accO[128][64] after walk)
//   keys   [1024] u64    : 8192  @ 65536
//   lpairs [1024] u32    : 4096  @ 73728
//   gid    [256] i32     : 1024  @ 77824
//   cnt256 [256] i32     : 1024  @ 80896   (gap 78848..80895 unused)
//   scn    [256] i32     : 1024  @ 81920
//   rep    [128] i32     : 512   @ 82944
//   red    [8] u64       : 64    @ 83456
//   bkey   u64           : 8     @ 83520
//   misc   [4] i32       : 16    @ 83528
#define SMEM_F 83584

__device__ __forceinline__ unsigned mono_f32(float s) {
  unsigned u = __float_as_uint(s);
  return (u & 0x80000000u) ? ~u : (u | 0x80000000u);
}

__device__ __forceinline__ unsigned long long shflx64(unsigned long long x, int m) {
  unsigned lo = (unsigned)x, hi = (unsigned)(x >> 32);
  lo = __shfl_xor(lo, m);
  hi = __shfl_xor(hi, m);
  return ((unsigned long long)hi << 32) | lo;
}

// invert T -> (ti, tj) on the 8x4 tile grid: ti in [0,32), tj in [2*ti, 64)
__device__ __forceinline__ void tile84(int T, int& tio, int& tjo) {
  float tf = (65.0f - sqrtf(4225.0f - 4.0f * (float)T)) * 0.5f;
  int t = (int)tf;
  if (t < 0) t = 0;
  if (t > 31) t = 31;
  while (t < 31 && 65 * (t + 1) - (t + 1) * (t + 1) <= T) ++t;
  while (t > 0 && 65 * t - t * t > T) --t;
  tio = t;
  tjo = 2 * t + (T - (65 * t - t * t));
}

#define CEX(a, b, up)                         \
  do {                                        \
    unsigned long long _a = (a), _b = (b);    \
    bool _sw = (up) ? (_a < _b) : (_a > _b);  \
    if (_sw) { (a) = _b; (b) = _a; }          \
  } while (0)

#define KEEP(v, o, km) ((km) ? ((v) > (o) ? (v) : (o)) : ((v) < (o) ? (v) : (o)))

// ---- 512-thread normalize (bit-identical chain to all passing rounds) ----
__device__ __forceinline__ void normalize_to_knT(const float* __restrict__ K,
                                                 float* __restrict__ knT,
                                                 int b, int tid) {
  const int t = tid >> 1, h = tid & 1;
  const float* kp = K + ((size_t)b * NTOK + t) * DIM + h * 32;
  double ss = 0.0;
  float vals[32];
#pragma unroll
  for (int q = 0; q < 8; ++q) {
    float4 v4 = *reinterpret_cast<const float4*>(kp + q * 4);
    vals[q * 4 + 0] = v4.x; vals[q * 4 + 1] = v4.y;
    vals[q * 4 + 2] = v4.z; vals[q * 4 + 3] = v4.w;
    ss += (double)v4.x * v4.x + (double)v4.y * v4.y +
          (double)v4.z * v4.z + (double)v4.w * v4.w;
  }
  double other = __shfl_xor(ss, 1);
  double nrm = sqrt(ss + other);
#pragma unroll
  for (int q = 0; q < 32; ++q)
    knT[(h * 32 + q) * NTOK + t] = (float)((double)vals[q] / nrm);
}

// ============ single fused kernel: norm + gram + sort + serial walk + epilogue ============
// grid 128 (1 WG/batch), block 512. R7 structure with the R4/R10 serial-shfl walk.
__global__ __launch_bounds__(512) void gm_all(const float* __restrict__ K,
                                              const float* __restrict__ V,
                                              float* __restrict__ OUT) {
  extern __shared__ char smem[];
  float* knT = (float*)smem;
  float* accO = (float*)smem;  // alias: valid only after knT is dead
  unsigned long long* keys = (unsigned long long*)(smem + 65536);
  unsigned* lpairs = (unsigned*)(smem + 73728);
  int* gid = (int*)(smem + 77824);
  int* cnt256 = (int*)(smem + 80896);
  int* scn = (int*)(smem + 81920);
  int* rep = (int*)(smem + 82944);
  unsigned long long* red = (unsigned long long*)(smem + 83456);
  unsigned long long* bkey = (unsigned long long*)(smem + 83520);
  int* misc = (int*)(smem + 83528);

  const int tid = threadIdx.x;
  const int lane = tid & 63;
  const int wid = tid >> 6;
  const int b = blockIdx.x;

  if (tid == 0) { misc[0] = 0; misc[1] = 0; }
  if (tid < NTOK) gid[tid] = tid;

  // ---- phase 1: normalize -> knT[d][t] ----
  normalize_to_knT(K, knT, b, tid);
  __syncthreads();

  // ---- phase 2: f32 screen over 8x4 register tiles -> (i,j) pair list ----
  for (int t = tid; t < NTILES84; t += 512) {
    int ti, tj;
    tile84(t, ti, tj);
    const int i0 = ti * 8, j0 = tj * 4;
    float acc[8][4] = {};
#pragma unroll 4
    for (int d = 0; d < 64; ++d) {
      const float* row = knT + d * NTOK;
      const float4 a0 = *reinterpret_cast<const float4*>(row + i0);
      const float4 a1 = *reinterpret_cast<const float4*>(row + i0 + 4);
      const float4 bv = *reinterpret_cast<const float4*>(row + j0);
      const float aa[8] = {a0.x, a0.y, a0.z, a0.w, a1.x, a1.y, a1.z, a1.w};
      const float bb[4] = {bv.x, bv.y, bv.z, bv.w};
#pragma unroll
      for (int r = 0; r < 8; ++r)
#pragma unroll
        for (int c = 0; c < 4; ++c)
          acc[r][c] = fmaf(aa[r], bb[c], acc[r][c]);
    }
#pragma unroll
    for (int r = 0; r < 8; ++r)
#pragma unroll
      for (int c = 0; c < 4; ++c) {
        const int i = i0 + r, j = j0 + c;
        if (i < j && acc[r][c] >= SCREEN) {
          const int idx = atomicAdd(&misc[0], 1);
          if (idx < PCAP) lpairs[idx] = (unsigned)((i << 8) | j);
        }
      }
  }
  __syncthreads();

  // ---- phase 3: compact exact-f64 recompute -> keys[] in LDS ----
  const int npRaw = misc[0];
  const int np = npRaw > PCAP ? PCAP : npRaw;
  const bool fullFB = (npRaw > PCAP);
  for (int e = tid; e < np; e += 512) {
    const unsigned p = lpairs[e];
    const int i = (int)(p >> 8), j = (int)(p & 255u);
    double s = 0.0;
    for (int d = 0; d < 64; ++d)
      s = fma((double)knT[d * NTOK + i], (double)knT[d * NTOK + j], s);
    const float sf = (float)s;
    if (sf >= KAPPA) {
      const unsigned long long key =
          ((unsigned long long)mono_f32(sf) << 16) |
          (unsigned)(65535 - ((i << 8) | j));
      const int idx = atomicAdd(&misc[1], 1);
      keys[idx] = key;  // idx < np <= CAP always
    }
  }
  if (tid == 0) misc[3] = fullFB ? 0 : NMERGE;
  __syncthreads();
  const int nk = misc[1];

  // ---- phase 4: bitonic sort (descending) of 1024 keys, 2 keys/thread ----
  {
    const int e0 = 2 * tid;
    unsigned long long v0 = (e0 + 0 < nk) ? keys[e0 + 0] : 0ULL;
    unsigned long long v1 = (e0 + 1 < nk) ? keys[e0 + 1] : 0ULL;
    for (int kk = 2; kk <= CAP; kk <<= 1) {
      for (int jj = kk >> 1; jj > 0; jj >>= 1) {
        if (jj >= 128) {
          __syncthreads();
          keys[e0] = v0; keys[e0 + 1] = v1;
          __syncthreads();
          const int p0 = e0 ^ jj;
          const unsigned long long o0 = keys[p0], o1 = keys[p0 + 1];
          const bool km = ((e0 & kk) == 0) == ((e0 & jj) == 0);
          v0 = KEEP(v0, o0, km); v1 = KEEP(v1, o1, km);
        } else if (jj >= 2) {
          const int m = jj >> 1;
          const unsigned long long o0 = shflx64(v0, m), o1 = shflx64(v1, m);
          const bool km = ((e0 & kk) == 0) == ((e0 & jj) == 0);
          v0 = KEEP(v0, o0, km); v1 = KEEP(v1, o1, km);
        } else {
          const bool up = ((e0 & kk) == 0);
          CEX(v0, v1, up);
        }
      }
    }
    __syncthreads();
    keys[e0] = v0; keys[e0 + 1] = v1;
  }
  __syncthreads();

  // ---- phase 5: serial-shfl walk (wave 0), gid entirely in registers ----
  if (misc[3] == NMERGE && wid == 0) {
    int rg0 = lane, rg1 = 64 + lane, rg2 = 128 + lane, rg3 = 192 + lane;
    int done = 0;
    for (int cursor = 0; cursor < nk && done < NMERGE; cursor += 64) {
      const int idx = cursor + lane;
      const unsigned long long key = (idx < nk) ? keys[idx] : 0ULL;
      const int pi = 255 - (int)((key >> 8) & 255);
      const int pj = 255 - (int)(key & 255);
      const int sli = pi & 63, ssi = pi >> 6;
      const int slj = pj & 63, ssj = pj >> 6;
      const int a0 = __shfl(rg0, sli), a1 = __shfl(rg1, sli),
                a2 = __shfl(rg2, sli), a3 = __shfl(rg3, sli);
      const int b0 = __shfl(rg0, slj), b1 = __shfl(rg1, slj),
                b2 = __shfl(rg2, slj), b3 = __shfl(rg3, slj);
      int gpi = (ssi == 0) ? a0 : (ssi == 1) ? a1 : (ssi == 2) ? a2 : a3;
      int gpj = (ssj == 0) ? b0 : (ssj == 1) ? b1 : (ssj == 2) ? b2 : b3;
      if (key == 0ULL) { gpi = 0; gpj = 0; }
      for (;;) {
        const unsigned long long mask = __ballot(gpi != gpj);
        if (!mask) break;
        const int f = __ffsll((long long)mask) - 1;
        const int gij = __shfl((gpi << 8) | gpj, f);
        const int gi = gij >> 8, gj = gij & 255;
        if (gpi == gi) gpi = gj;
        if (gpj == gi) gpj = gj;
        if (rg0 == gi) rg0 = gj;
        if (rg1 == gi) rg1 = gj;
        if (rg2 == gi) rg2 = gj;
        if (rg3 == gi) rg3 = gj;
        if (++done == NMERGE) break;
      }
    }
    gid[lane] = rg0; gid[64 + lane] = rg1;
    gid[128 + lane] = rg2; gid[192 + lane] = rg3;
    if (lane == 0) misc[3] = done;
  }
  __syncthreads();

  // ---- phase 6: exact fallback (cheap: knT already in LDS) ----
  {
    const int start = misc[3];
    for (int mg = start; mg < NMERGE; ++mg) {
      unsigned long long best = 0ULL;
      const int p = tid >> 2, q = tid & 3;
      const int jA = 128 + p, jB = 127 - p;
      const int lenA = jA;
      const int s0 = q * 64, s1 = (q == 3) ? 255 : (q * 64 + 64);
      for (int e = s0; e < s1; ++e) {
        const int i = (e < lenA) ? e : (e - lenA);
        const int j = (e < lenA) ? jA : jB;
        if (gid[i] != gid[j]) {
          double s = 0.0;
          for (int d = 0; d < 64; ++d)
            s = fma((double)knT[d * NTOK + i], (double)knT[d * NTOK + j], s);
          const unsigned long long key =
              ((unsigned long long)mono_f32((float)s) << 16) |
              (unsigned)(65535 - ((i << 8) | j));
          if (key > best) best = key;
        }
      }
#pragma unroll
      for (int off = 32; off; off >>= 1) {
        unsigned long long o = __shfl_down(best, off);
        if (o > best) best = o;
      }
      if (lane == 0) red[wid] = best;
      __syncthreads();
      if (tid == 0) {
        unsigned long long mx = red[0];
        for (int w = 1; w < 8; ++w)
          if (red[w] > mx) mx = red[w];
        bkey[0] = mx;
      }
      __syncthreads();
      const unsigned long long bk = bkey[0];
      const int pi = 255 - (int)((bk >> 8) & 255);
      const int pj = 255 - (int)(bk & 255);
      const int gi = gid[pi], gj = gid[pj];
      __syncthreads();
      if (tid < NTOK && gid[tid] == gi) gid[tid] = gj;
      __syncthreads();
    }
  }
  __syncthreads();
  // knT DEAD from here; accO (alias) becomes live.

  // ---- phase 7: sizes + single-wave prefix scan + slots ----
  if (tid < NTOK) cnt256[tid] = 0;
  for (int e = tid; e < NOUT * DIM; e += 512) accO[e] = 0.0f;
  __syncthreads();
  if (tid < NTOK) atomicAdd(&cnt256[gid[tid]], 1);
  __syncthreads();
  if (wid == 0) {
    const int t4 = lane * 4;
    const int c0 = cnt256[t4 + 0] != 0, c1 = cnt256[t4 + 1] != 0,
              c2 = cnt256[t4 + 2] != 0, c3 = cnt256[t4 + 3] != 0;
    const int tot = c0 + c1 + c2 + c3;
    int run = tot;
#pragma unroll
    for (int off = 1; off < 64; off <<= 1) {
      int o = __shfl_up(run, off);
      if (lane >= off) run += o;
    }
    const int bs = run - tot;
    scn[t4 + 0] = bs + c0;
    scn[t4 + 1] = bs + c0 + c1;
    scn[t4 + 2] = bs + c0 + c1 + c2;
    scn[t4 + 3] = bs + tot;
  }
  __syncthreads();
  if (tid < NTOK && cnt256[tid]) rep[scn[tid] - 1] = tid;
  __syncthreads();

  // ---- phase 8: accumulate V into slots (token tid>>1, half tid&1) ----
  {
    const int t = tid >> 1, h = tid & 1;
    const int slot = scn[gid[t]] - 1;
    const float* vp = V + ((size_t)b * NTOK + t) * DIM + h * 32;
    float* dst = accO + slot * DIM + h * 32;
#pragma unroll
    for (int q = 0; q < 8; ++q) {
      float4 v4 = *reinterpret_cast<const float4*>(vp + q * 4);
      atomicAdd(&dst[q * 4 + 0], v4.x);
      atomicAdd(&dst[q * 4 + 1], v4.y);
      atomicAdd(&dst[q * 4 + 2], v4.z);
      atomicAdd(&dst[q * 4 + 3], v4.w);
    }
  }
  __syncthreads();

  // ---- phase 9: write outputs ----
  float* outMain = OUT + (size_t)b * (NOUT * DIM);
  for (int e = tid; e < NOUT * DIM; e += 512) {
    const int o = e >> 6;
    const float sz = (float)cnt256[rep[o]];
    outMain[e] = accO[e] / sz;
  }
  float* outSz = OUT + (size_t)NB * NOUT * DIM + (size_t)b * NOUT;
  for (int o = tid; o < NOUT; o += 512) outSz[o] = (float)cnt256[rep[o]];
}

extern "C" void kernel_launch(void* const* d_in, const int* in_sizes, int n_in,
                              void* d_out, int out_size, void* d_ws, size_t ws_size,
                              hipStream_t stream) {
  const float* K = (const float*)d_in[0];
  const float* V = (const float*)d_in[1];
  float* OUT = (float*)d_out;
  (void)in_sizes; (void)n_in; (void)out_size; (void)d_ws; (void)ws_size;

  hipFuncSetAttribute(reinterpret_cast<const void*>(gm_all),
                      hipFuncAttributeMaxDynamicSharedMemorySize, SMEM_F);
  gm_all<<<dim3(NB), dim3(512), SMEM_F, stream>>>(K, V, OUT);
}

// Round 15
// 80.241 us; speedup vs baseline: 1.3330x; 1.0587x over previous
//
#include <hip/hip_runtime.h>
#include <stdint.h>

#define NTOK 256
#define NOUT 128
#define DIM 64
#define NB 128
#define CAP 1024
#define PCAP 1024
#define NMERGE 128
#define KAPPA 0.24f
#define SCREEN 0.2395f
#define NTILES84 1056

// LDS layout (bytes):
//   knT    [64][256] f32 : 65536 @ 0       (aliased by accO[128][64] after walk)
//   keys   [1024] u64    : 8192  @ 65536
//   lpairs [1024] u32    : 4096  @ 73728
//   gid    [256] i32     : 1024  @ 77824
//   claimA [256] u32     : 1024  @ 78848
//   gmap   [256] i32     : 1024  @ 79872
//   cnt256 [256] i32     : 1024  @ 80896
//   scn    [256] i32     : 1024  @ 81920
//   rep    [128] i32     : 512   @ 82944
//   red    [8] u64       : 64    @ 83456
//   bkey   u64           : 8     @ 83520
//   misc   [4] i32       : 16    @ 83528
#define SMEM_F 83584

__device__ __forceinline__ unsigned mono_f32(float s) {
  unsigned u = __float_as_uint(s);
  return (u & 0x80000000u) ? ~u : (u | 0x80000000u);
}

__device__ __forceinline__ unsigned long long shflx64(unsigned long long x, int m) {
  unsigned lo = (unsigned)x, hi = (unsigned)(x >> 32);
  lo = __shfl_xor(lo, m);
  hi = __shfl_xor(hi, m);
  return ((unsigned long long)hi << 32) | lo;
}

// invert T -> (ti, tj) on the 8x4 tile grid: ti in [0,32), tj in [2*ti, 64)
// cum(ti) = 65*ti - ti*ti
__device__ __forceinline__ void tile84(int T, int& tio, int& tjo) {
  float tf = (65.0f - sqrtf(4225.0f - 4.0f * (float)T)) * 0.5f;
  int t = (int)tf;
  if (t < 0) t = 0;
  if (t > 31) t = 31;
  while (t < 31 && 65 * (t + 1) - (t + 1) * (t + 1) <= T) ++t;
  while (t > 0 && 65 * t - t * t > T) --t;
  tio = t;
  tjo = 2 * t + (T - (65 * t - t * t));
}

#define CEX(a, b, up)                         \
  do {                                        \
    unsigned long long _a = (a), _b = (b);    \
    bool _sw = (up) ? (_a < _b) : (_a > _b);  \
    if (_sw) { (a) = _b; (b) = _a; }          \
  } while (0)

#define KEEP(v, o, km) ((km) ? ((v) > (o) ? (v) : (o)) : ((v) < (o) ? (v) : (o)))

// ============ fused kernel: gram + screen + sort + claim-walk + epilogue (R7) ============
// grid 128 (1 WG/batch), block 512.
__global__ __launch_bounds__(512) void gm_fused(const float* __restrict__ K,
                                                const float* __restrict__ V,
                                                float* __restrict__ OUT) {
  extern __shared__ char smem[];
  float* knT = (float*)smem;
  float* accO = (float*)smem;  // alias: valid only after knT is dead
  unsigned long long* keys = (unsigned long long*)(smem + 65536);
  unsigned* lpairs = (unsigned*)(smem + 73728);
  int* gid = (int*)(smem + 77824);
  unsigned* claimA = (unsigned*)(smem + 78848);
  int* gmap = (int*)(smem + 79872);
  int* cnt256 = (int*)(smem + 80896);
  int* scn = (int*)(smem + 81920);
  int* rep = (int*)(smem + 82944);
  unsigned long long* red = (unsigned long long*)(smem + 83456);
  unsigned long long* bkey = (unsigned long long*)(smem + 83520);
  int* misc = (int*)(smem + 83528);

  const int tid = threadIdx.x;
  const int lane = tid & 63;
  const int wid = tid >> 6;
  const int b = blockIdx.x;

  if (tid == 0) { misc[0] = 0; misc[1] = 0; }
  if (tid < NTOK) {
    gid[tid] = tid;
    claimA[tid] = 0xFFFFFFFFu;
    gmap[tid] = -1;
  }

  // ---- phase 1: normalize -> knT[d][t] (bit-identical to prior rounds) ----
  {
    const int t = tid >> 1, h = tid & 1;
    const float* kp = K + ((size_t)b * NTOK + t) * DIM + h * 32;
    double ss = 0.0;
    float vals[32];
#pragma unroll
    for (int q = 0; q < 8; ++q) {
      float4 v4 = *reinterpret_cast<const float4*>(kp + q * 4);
      vals[q * 4 + 0] = v4.x; vals[q * 4 + 1] = v4.y;
      vals[q * 4 + 2] = v4.z; vals[q * 4 + 3] = v4.w;
      ss += (double)v4.x * v4.x + (double)v4.y * v4.y +
            (double)v4.z * v4.z + (double)v4.w * v4.w;
    }
    double other = __shfl_xor(ss, 1);
    double nrm = sqrt(ss + other);
#pragma unroll
    for (int q = 0; q < 32; ++q)
      knT[(h * 32 + q) * NTOK + t] = (float)((double)vals[q] / nrm);
  }
  __syncthreads();

  // ---- phase 2: f32 screen over 8x4 register tiles -> (i,j) pair list ----
  for (int t = tid; t < NTILES84; t += 512) {
    int ti, tj;
    tile84(t, ti, tj);
    const int i0 = ti * 8, j0 = tj * 4;

    float acc[8][4] = {};
#pragma unroll 4
    for (int d = 0; d < 64; ++d) {
      const float* row = knT + d * NTOK;
      const float4 a0 = *reinterpret_cast<const float4*>(row + i0);
      const float4 a1 = *reinterpret_cast<const float4*>(row + i0 + 4);
      const float4 bv = *reinterpret_cast<const float4*>(row + j0);
      const float aa[8] = {a0.x, a0.y, a0.z, a0.w, a1.x, a1.y, a1.z, a1.w};
      const float bb[4] = {bv.x, bv.y, bv.z, bv.w};
#pragma unroll
      for (int r = 0; r < 8; ++r)
#pragma unroll
        for (int c = 0; c < 4; ++c)
          acc[r][c] = fmaf(aa[r], bb[c], acc[r][c]);
    }
#pragma unroll
    for (int r = 0; r < 8; ++r)
#pragma unroll
      for (int c = 0; c < 4; ++c) {
        const int i = i0 + r, j = j0 + c;
        if (i < j && acc[r][c] >= SCREEN) {
          const int idx = atomicAdd(&misc[0], 1);
          if (idx < PCAP) lpairs[idx] = (unsigned)((i << 8) | j);
        }
      }
  }
  __syncthreads();

  // ---- phase 3: compact exact-f64 recompute -> keys[] in LDS ----
  const int npRaw = misc[0];
  const int np = npRaw > PCAP ? PCAP : npRaw;
  const bool fullFB = (npRaw > PCAP);
  for (int e = tid; e < np; e += 512) {
    const unsigned p = lpairs[e];
    const int i = (int)(p >> 8), j = (int)(p & 255u);
    double s = 0.0;
    for (int d = 0; d < 64; ++d)
      s = fma((double)knT[d * NTOK + i], (double)knT[d * NTOK + j], s);
    const float sf = (float)s;
    if (sf >= KAPPA) {
      const unsigned long long key =
          ((unsigned long long)mono_f32(sf) << 16) |
          (unsigned)(65535 - ((i << 8) | j));
      const int idx = atomicAdd(&misc[1], 1);
      keys[idx] = key;  // idx < np <= CAP always
    }
  }
  if (tid == 0) misc[3] = fullFB ? 0 : NMERGE;
  __syncthreads();
  const int nk = misc[1];

  // ---- phase 4: bitonic sort (descending) of 1024 keys, 2 keys/thread ----
  {
    const int e0 = 2 * tid;
    unsigned long long v0 = (e0 + 0 < nk) ? keys[e0 + 0] : 0ULL;
    unsigned long long v1 = (e0 + 1 < nk) ? keys[e0 + 1] : 0ULL;

    for (int kk = 2; kk <= CAP; kk <<= 1) {
      for (int jj = kk >> 1; jj > 0; jj >>= 1) {
        if (jj >= 128) {
          __syncthreads();
          keys[e0] = v0; keys[e0 + 1] = v1;
          __syncthreads();
          const int p0 = e0 ^ jj;
          const unsigned long long o0 = keys[p0], o1 = keys[p0 + 1];
          const bool km = ((e0 & kk) == 0) == ((e0 & jj) == 0);
          v0 = KEEP(v0, o0, km); v1 = KEEP(v1, o1, km);
        } else if (jj >= 2) {
          const int m = jj >> 1;
          const unsigned long long o0 = shflx64(v0, m), o1 = shflx64(v1, m);
          const bool km = ((e0 & kk) == 0) == ((e0 & jj) == 0);
          v0 = KEEP(v0, o0, km); v1 = KEEP(v1, o1, km);
        } else {
          const bool up = ((e0 & kk) == 0);
          CEX(v0, v1, up);
        }
      }
    }
    __syncthreads();
    keys[e0] = v0; keys[e0 + 1] = v1;
  }
  __syncthreads();

  // ---- phase 5: wave-0 walk over sorted keys (parallel disjoint rounds) ----
  if (!fullFB && wid == 0) {
    int done = 0;
    for (int cursor = 0; cursor < nk && done < NMERGE; cursor += 64) {
      const int idx = cursor + lane;
      const unsigned long long key = (idx < nk) ? keys[idx] : 0ULL;
      const int pi = 255 - (int)((key >> 8) & 255);
      const int pj = 255 - (int)(key & 255);
      int gpi = gid[pi];
      int gpj = gid[pj];
      if (key == 0ULL) { gpi = 0; gpj = 0; }  // padding -> invalid
      int rg0 = gid[lane], rg1 = gid[64 + lane],
          rg2 = gid[128 + lane], rg3 = gid[192 + lane];

      unsigned long long valid = __ballot(gpi != gpj);
      if (done + (int)__popcll(valid) < NMERGE) {
        // parallel rounds: commit all prefix-disjoint merges
        while (valid) {
          const bool v = (gpi != gpj);
          if (v) {
            atomicMin(&claimA[gpi], (unsigned)lane);
            atomicMin(&claimA[gpj], (unsigned)lane);
          }
          __threadfence_block();
          const bool win = v && (claimA[gpi] == (unsigned)lane) &&
                           (claimA[gpj] == (unsigned)lane);
          if (win) gmap[gpi] = gpj;  // merge group gpi INTO gpj
          __threadfence_block();
          const int ogpi = gpi, ogpj = gpj;
          {
            const int m0 = gmap[rg0], m1 = gmap[rg1],
                      m2 = gmap[rg2], m3 = gmap[rg3];
            const int mi = gmap[ogpi], mj = gmap[ogpj];
            if (m0 >= 0) rg0 = m0;
            if (m1 >= 0) rg1 = m1;
            if (m2 >= 0) rg2 = m2;
            if (m3 >= 0) rg3 = m3;
            if (mi >= 0) gpi = mi;
            if (mj >= 0) gpj = mj;
          }
          if (v) { claimA[ogpi] = 0xFFFFFFFFu; claimA[ogpj] = 0xFFFFFFFFu; }
          if (win) gmap[ogpi] = -1;
          __threadfence_block();
          done += (int)__popcll(__ballot(win));
          valid = __ballot(gpi != gpj);
        }
      } else {
        // serial mode near budget: exact cutoff at NMERGE
        for (;;) {
          const unsigned long long mask = __ballot(gpi != gpj);
          if (!mask) break;
          const int f = __ffsll((long long)mask) - 1;
          const int gij = __shfl((gpi << 8) | gpj, f);
          const int gi = gij >> 8, gj = gij & 255;
          if (gpi == gi) gpi = gj;
          if (gpj == gi) gpj = gj;
          if (rg0 == gi) rg0 = gj;
          if (rg1 == gi) rg1 = gj;
          if (rg2 == gi) rg2 = gj;
          if (rg3 == gi) rg3 = gj;
          if (++done == NMERGE) break;
        }
      }
      gid[lane] = rg0; gid[64 + lane] = rg1;
      gid[128 + lane] = rg2; gid[192 + lane] = rg3;
      __threadfence_block();
    }
    if (lane == 0) misc[3] = done;
  }
  __syncthreads();

  // ---- phase 6: exact fallback (never taken in practice), uses knT ----
  {
    const int start = misc[3];
    for (int mg = start; mg < NMERGE; ++mg) {
      unsigned long long best = 0ULL;
      const int p = tid >> 2, q = tid & 3;
      const int jA = 128 + p, jB = 127 - p;
      const int lenA = jA;
      const int s0 = q * 64, s1 = (q == 3) ? 255 : (q * 64 + 64);
      for (int e = s0; e < s1; ++e) {
        const int i = (e < lenA) ? e : (e - lenA);
        const int j = (e < lenA) ? jA : jB;
        if (gid[i] != gid[j]) {
          double s = 0.0;
          for (int d = 0; d < 64; ++d)
            s = fma((double)knT[d * NTOK + i], (double)knT[d * NTOK + j], s);
          const unsigned long long key =
              ((unsigned long long)mono_f32((float)s) << 16) |
              (unsigned)(65535 - ((i << 8) | j));
          if (key > best) best = key;
        }
      }
#pragma unroll
      for (int off = 32; off; off >>= 1) {
        unsigned long long o = __shfl_down(best, off);
        if (o > best) best = o;
      }
      if (lane == 0) red[wid] = best;
      __syncthreads();
      if (tid == 0) {
        unsigned long long mx = red[0];
        for (int w = 1; w < 8; ++w)
          if (red[w] > mx) mx = red[w];
        bkey[0] = mx;
      }
      __syncthreads();
      const unsigned long long bk = bkey[0];
      const int pi = 255 - (int)((bk >> 8) & 255);
      const int pj = 255 - (int)(bk & 255);
      const int gi = gid[pi], gj = gid[pj];
      __syncthreads();
      if (tid < NTOK && gid[tid] == gi) gid[tid] = gj;
      __syncthreads();
    }
  }
  __syncthreads();
  // knT is DEAD from here; accO (alias of knT) becomes live.

  // ---- phase 7: sizes + single-wave prefix scan + slots ----
  if (tid < NTOK) cnt256[tid] = 0;
  for (int e = tid; e < NOUT * DIM; e += 512) accO[e] = 0.0f;
  __syncthreads();
  if (tid < NTOK) atomicAdd(&cnt256[gid[tid]], 1);
  __syncthreads();
  if (wid == 0) {
    const int t4 = lane * 4;
    const int c0 = cnt256[t4 + 0] != 0, c1 = cnt256[t4 + 1] != 0,
              c2 = cnt256[t4 + 2] != 0, c3 = cnt256[t4 + 3] != 0;
    const int tot = c0 + c1 + c2 + c3;
    int run = tot;
#pragma unroll
    for (int off = 1; off < 64; off <<= 1) {
      int o = __shfl_up(run, off);
      if (lane >= off) run += o;
    }
    const int bs = run - tot;
    scn[t4 + 0] = bs + c0;
    scn[t4 + 1] = bs + c0 + c1;
    scn[t4 + 2] = bs + c0 + c1 + c2;
    scn[t4 + 3] = bs + tot;
  }
  __syncthreads();
  if (tid < NTOK && cnt256[tid]) rep[scn[tid] - 1] = tid;
  __syncthreads();

  // ---- phase 8: accumulate V into slots (token tid>>1, half tid&1) ----
  {
    const int t = tid >> 1, h = tid & 1;
    const int slot = scn[gid[t]] - 1;
    const float* vp = V + ((size_t)b * NTOK + t) * DIM + h * 32;
    float* dst = accO + slot * DIM + h * 32;
#pragma unroll
    for (int q = 0; q < 8; ++q) {
      float4 v4 = *reinterpret_cast<const float4*>(vp + q * 4);
      atomicAdd(&dst[q * 4 + 0], v4.x);
      atomicAdd(&dst[q * 4 + 1], v4.y);
      atomicAdd(&dst[q * 4 + 2], v4.z);
      atomicAdd(&dst[q * 4 + 3], v4.w);
    }
  }
  __syncthreads();

  // ---- phase 9: write outputs ----
  float* outMain = OUT + (size_t)b * (NOUT * DIM);
  for (int e = tid; e < NOUT * DIM; e += 512) {
    const int o = e >> 6;
    const float sz = (float)cnt256[rep[o]];
    outMain[e] = accO[e] / sz;
  }
  float* outSz = OUT + (size_t)NB * NOUT * DIM + (size_t)b * NOUT;
  for (int o = tid; o < NOUT; o += 512) outSz[o] = (float)cnt256[rep[o]];
}

extern "C" void kernel_launch(void* const* d_in, const int* in_sizes, int n_in,
                              void* d_out, int out_size, void* d_ws, size_t ws_size,
                              hipStream_t stream) {
  const float* K = (const float*)d_in[0];
  const float* V = (const float*)d_in[1];
  float* OUT = (float*)d_out;
  (void)in_sizes; (void)n_in; (void)out_size; (void)d_ws; (void)ws_size;

  hipFuncSetAttribute(reinterpret_cast<const void*>(gm_fused),
                      hipFuncAttributeMaxDynamicSharedMemorySize, SMEM_F);
  gm_fused<<<dim3(NB), dim3(512), SMEM_F, stream>>>(K, V, OUT);
}